// Round 1
// baseline (1014.676 us; speedup 1.0000x reference)
//
#include <hip/hip_runtime.h>
#include <math.h>

#define T_  1024
#define H_  1024
#define DK_ 512
#define DV_ 1024
#define LR_ 16

// ---------------------------------------------------------------------------
// Generic fp32 GEMM: C[M,N] = A[M,K] @ B[K,N], all row-major.
// 64x64 tile, BK=16, 256 threads, 4x4 per thread.
// ---------------------------------------------------------------------------
__global__ __launch_bounds__(256) void gemm_f32(const float* __restrict__ A,
                                                const float* __restrict__ B,
                                                float* __restrict__ C,
                                                int M, int N, int K) {
  __shared__ float As[16][65];   // transposed A tile, padded
  __shared__ float Bs[16][64];
  int tid = threadIdx.x;
  int bm = blockIdx.y << 6, bn = blockIdx.x << 6;
  int tx4 = (tid & 15) << 2, ty4 = (tid >> 4) << 2;
  float acc[4][4] = {{0.f}};

  int ar = tid >> 2;            // 0..63 A-tile row
  int ac = (tid & 3) << 2;      // 0,4,8,12 k-offset
  int bk = tid >> 4;            // 0..15 B-tile k row
  int bc = (tid & 15) << 2;     // 0..60 col offset

  for (int k0 = 0; k0 < K; k0 += 16) {
    float4 a4 = *(const float4*)&A[(size_t)(bm + ar) * K + k0 + ac];
    float4 b4 = *(const float4*)&B[(size_t)(k0 + bk) * N + bn + bc];
    __syncthreads();   // previous compute done reading LDS
    As[ac + 0][ar] = a4.x;
    As[ac + 1][ar] = a4.y;
    As[ac + 2][ar] = a4.z;
    As[ac + 3][ar] = a4.w;
    *(float4*)&Bs[bk][bc] = b4;
    __syncthreads();
#pragma unroll
    for (int kk = 0; kk < 16; ++kk) {
      float av[4];
      av[0] = As[kk][ty4 + 0];
      av[1] = As[kk][ty4 + 1];
      av[2] = As[kk][ty4 + 2];
      av[3] = As[kk][ty4 + 3];
      float4 bq = *(const float4*)&Bs[kk][tx4];
      float bv[4] = {bq.x, bq.y, bq.z, bq.w};
#pragma unroll
      for (int i = 0; i < 4; ++i)
#pragma unroll
        for (int j = 0; j < 4; ++j)
          acc[i][j] = fmaf(av[i], bv[j], acc[i][j]);
    }
  }
#pragma unroll
  for (int i = 0; i < 4; ++i) {
    float4 o = make_float4(acc[i][0], acc[i][1], acc[i][2], acc[i][3]);
    *(float4*)&C[(size_t)(bm + (ty4 >> 2) * 4 + i) * N + bn + tx4] = o;
  }
}

// ---------------------------------------------------------------------------
// xg1[2048,16] = x[2048,1024] @ Wgk1[1024,16]
// ---------------------------------------------------------------------------
__global__ __launch_bounds__(256) void lr1_kernel(const float* __restrict__ x,
                                                  const float* __restrict__ Wgk1,
                                                  float* __restrict__ xg1) {
  int gid = blockIdx.x * 256 + threadIdx.x;   // 2048*16 threads
  int m = gid >> 4, j = gid & 15;
  const float* xr = x + (size_t)m * H_;
  float s = 0.f;
  for (int k = 0; k < H_; ++k) s = fmaf(xr[k], Wgk1[k * LR_ + j], s);
  xg1[gid] = s;
}

// ---------------------------------------------------------------------------
// gk[2048,512] = log_sigmoid(xg1 @ Wgk2 + bgk2) / 16
// ---------------------------------------------------------------------------
__global__ __launch_bounds__(256) void gk_kernel(const float* __restrict__ xg1,
                                                 const float* __restrict__ Wgk2,
                                                 const float* __restrict__ bgk2,
                                                 float* __restrict__ gk) {
  int gid = blockIdx.x * 256 + threadIdx.x;   // 2048*512 threads
  int m = gid >> 9, n = gid & 511;
  const float* xr = xg1 + m * LR_;
  float s = bgk2[n];
#pragma unroll
  for (int r = 0; r < LR_; ++r) s = fmaf(xr[r], Wgk2[r * DK_ + n], s);
  // stable log_sigmoid(s) = min(s,0) - log1p(exp(-|s|))
  float ls = fminf(s, 0.f) - log1pf(__expf(-fabsf(s)));
  gk[gid] = ls * (1.0f / 16.0f);
}

// ---------------------------------------------------------------------------
// Sequential GLA scan. Grid: 64 blocks = (b:2) x (h:4) x (vslice:8).
// Each block owns state S[128 k-rows][32 v-cols] in registers
// (256 threads x 16 cells). Per step:
//   S = exp(gk_t) * S + k_t (x) v_t ;  o_t = q_t^T S * scale
// ---------------------------------------------------------------------------
__global__ __launch_bounds__(256) void scan_kernel(const float* __restrict__ Q,
                                                   const float* __restrict__ K,
                                                   const float* __restrict__ V,
                                                   const float* __restrict__ GK,
                                                   float* __restrict__ O) {
  int bid = blockIdx.x;
  int vs = bid & 7, h = (bid >> 3) & 3, b = bid >> 5;
  int tid = threadIdx.x;
  int w = tid >> 6, l = tid & 63;
  int c = l & 31;                        // v-col within slice
  int r0 = (w << 5) + ((l >> 5) << 4);   // first of 16 k-rows

  __shared__ float ks[128], qs[128], ds[128], vsm[32];
  __shared__ float opart[4][32];

  float S[16];
#pragma unroll
  for (int i = 0; i < 16; ++i) S[i] = 0.f;
  const float scale = 0.08838834764831845f;  // dk^-0.5

  size_t baseQK = (size_t)b * T_ * DK_ + h * 128;
  size_t baseV  = (size_t)b * T_ * DV_ + h * 256 + vs * 32;
  size_t baseO  = (size_t)b * T_ * DV_ + h * 256 + vs * 32;

  // prefetch t = 0
  float rk = 0.f, rq = 0.f, rg = 0.f, rv = 0.f;
  int u = tid - 128;
  if (tid < 128) { rk = K[baseQK + tid]; rg = GK[baseQK + tid]; }
  else           { rq = Q[baseQK + u]; if (u < 32) rv = V[baseV + u]; }

  for (int t = 0; t < T_; ++t) {
    // stage current step into LDS
    if (tid < 128) { ks[tid] = rk; ds[tid] = __expf(rg); }
    else           { qs[u] = rq; if (u < 32) vsm[u] = rv; }
    __syncthreads();
    // prefetch next step (overlaps with compute below)
    if (t + 1 < T_) {
      size_t nQK = baseQK + (size_t)(t + 1) * DK_;
      size_t nV  = baseV + (size_t)(t + 1) * DV_;
      if (tid < 128) { rk = K[nQK + tid]; rg = GK[nQK + tid]; }
      else           { rq = Q[nQK + u]; if (u < 32) rv = V[nV + u]; }
    }
    float vv = vsm[c];
    float o = 0.f;
#pragma unroll
    for (int i = 0; i < 16; ++i) {
      float dec = ds[r0 + i];
      float kk  = ks[r0 + i];
      float qq  = qs[r0 + i];
      S[i] = fmaf(dec, S[i], kk * vv);
      o = fmaf(qq, S[i], o);
    }
    // reduce over the two 16-row halves (lanes l and l^32 share a column)
    o += __shfl_xor(o, 32);
    if (l < 32) opart[w][l] = o;
    __syncthreads();
    if (tid < 32) {
      float s = (opart[0][tid] + opart[1][tid]) + (opart[2][tid] + opart[3][tid]);
      O[baseO + (size_t)t * DV_ + tid] = s * scale;
    }
    // next iteration's LDS stores are fenced by the barrier at loop top
  }
}

// ---------------------------------------------------------------------------
// Fused RMSNorm (over dv=256) * gw * swish(g). Rows = (b,t,h) = 8192.
// ---------------------------------------------------------------------------
__global__ __launch_bounds__(256) void norm_gate(const float* __restrict__ Oraw,
                                                 const float* __restrict__ G,
                                                 const float* __restrict__ gw,
                                                 float* __restrict__ On) {
  int row = blockIdx.x;       // 0..8191, layout [2048][4][256] == [2048][1024]
  int j = threadIdx.x;
  size_t idx = (size_t)row * 256 + j;
  float o = Oraw[idx];
  float ss = o * o;
#pragma unroll
  for (int off = 32; off > 0; off >>= 1) ss += __shfl_xor(ss, off);
  __shared__ float red[4];
  if ((j & 63) == 0) red[j >> 6] = ss;
  __syncthreads();
  float tot = (red[0] + red[1]) + (red[2] + red[3]);
  float r = rsqrtf(tot * (1.0f / 256.0f) + 1e-5f);
  float gval = G[idx];
  float sw = gval / (1.0f + __expf(-gval));   // g * sigmoid(g)
  On[idx] = o * r * gw[j] * sw;
}

// ---------------------------------------------------------------------------
extern "C" void kernel_launch(void* const* d_in, const int* in_sizes, int n_in,
                              void* d_out, int out_size, void* d_ws, size_t ws_size,
                              hipStream_t stream) {
  const float* x    = (const float*)d_in[0];
  const float* Wq   = (const float*)d_in[1];
  const float* Wk   = (const float*)d_in[2];
  const float* Wv   = (const float*)d_in[3];
  const float* Wgk1 = (const float*)d_in[4];
  const float* Wgk2 = (const float*)d_in[5];
  const float* bgk2 = (const float*)d_in[6];
  const float* Wg   = (const float*)d_in[7];
  const float* Wo   = (const float*)d_in[8];
  const float* gw   = (const float*)d_in[9];
  float* out = (float*)d_out;

  const size_t M = 2048;
  float* ws   = (float*)d_ws;
  float* q    = ws;               // 2048*512
  float* k    = q    + M * 512;   // 2048*512
  float* v    = k    + M * 512;   // 2048*1024
  float* g    = v    + M * 1024;  // 2048*1024
  float* xg1  = g    + M * 1024;  // 2048*16
  float* gk   = xg1  + M * 16;    // 2048*512
  float* oraw = gk   + M * 512;   // 2048*1024
  float* on   = oraw + M * 1024;  // 2048*1024

  dim3 blk(256);
  gemm_f32<<<dim3(DK_ / 64, M / 64), blk, 0, stream>>>(x, Wq, q, M, DK_, H_);
  gemm_f32<<<dim3(DK_ / 64, M / 64), blk, 0, stream>>>(x, Wk, k, M, DK_, H_);
  gemm_f32<<<dim3(DV_ / 64, M / 64), blk, 0, stream>>>(x, Wv, v, M, DV_, H_);
  gemm_f32<<<dim3(DV_ / 64, M / 64), blk, 0, stream>>>(x, Wg, g, M, DV_, H_);
  lr1_kernel<<<(M * 16) / 256, blk, 0, stream>>>(x, Wgk1, xg1);
  gk_kernel<<<(M * DK_) / 256, blk, 0, stream>>>(xg1, Wgk2, bgk2, gk);
  scan_kernel<<<64, blk, 0, stream>>>(q, k, v, gk, oraw);
  norm_gate<<<M * 4, blk, 0, stream>>>(oraw, g, gw, on);
  gemm_f32<<<dim3(H_ / 64, M / 64), blk, 0, stream>>>(on, Wo, out, M, H_, DV_);
}

// Round 2
// 440.836 us; speedup vs baseline: 2.3017x; 2.3017x over previous
//
#include <hip/hip_runtime.h>
#include <math.h>

#define T_  1024
#define H_  1024
#define DK_ 512
#define DV_ 1024
#define LR_ 16
#define CHUNK 64
#define NC 16
#define NBH 8

// ---------------------------------------------------------------------------
// Generic fp32 GEMM: C[M,N] = A[M,K] @ B[K,N], all row-major.
// 64x64 tile, BK=16, 256 threads, 4x4 per thread.
// ---------------------------------------------------------------------------
__global__ __launch_bounds__(256) void gemm_f32(const float* __restrict__ A,
                                                const float* __restrict__ B,
                                                float* __restrict__ C,
                                                int M, int N, int K) {
  __shared__ float As[16][65];
  __shared__ float Bs[16][64];
  int tid = threadIdx.x;
  int bm = blockIdx.y << 6, bn = blockIdx.x << 6;
  int tx4 = (tid & 15) << 2, ty4 = (tid >> 4) << 2;
  float acc[4][4] = {{0.f}};

  int ar = tid >> 2;
  int ac = (tid & 3) << 2;
  int bk = tid >> 4;
  int bc = (tid & 15) << 2;

  for (int k0 = 0; k0 < K; k0 += 16) {
    float4 a4 = *(const float4*)&A[(size_t)(bm + ar) * K + k0 + ac];
    float4 b4 = *(const float4*)&B[(size_t)(k0 + bk) * N + bn + bc];
    __syncthreads();
    As[ac + 0][ar] = a4.x;
    As[ac + 1][ar] = a4.y;
    As[ac + 2][ar] = a4.z;
    As[ac + 3][ar] = a4.w;
    *(float4*)&Bs[bk][bc] = b4;
    __syncthreads();
#pragma unroll
    for (int kk = 0; kk < 16; ++kk) {
      float av[4];
      av[0] = As[kk][ty4 + 0];
      av[1] = As[kk][ty4 + 1];
      av[2] = As[kk][ty4 + 2];
      av[3] = As[kk][ty4 + 3];
      float4 bq = *(const float4*)&Bs[kk][tx4];
      float bv[4] = {bq.x, bq.y, bq.z, bq.w};
#pragma unroll
      for (int i = 0; i < 4; ++i)
#pragma unroll
        for (int j = 0; j < 4; ++j)
          acc[i][j] = fmaf(av[i], bv[j], acc[i][j]);
    }
  }
#pragma unroll
  for (int i = 0; i < 4; ++i) {
    float4 o = make_float4(acc[i][0], acc[i][1], acc[i][2], acc[i][3]);
    *(float4*)&C[(size_t)(bm + ty4 + i) * N + bn + tx4] = o;
  }
}

// ---------------------------------------------------------------------------
__global__ __launch_bounds__(256) void lr1_kernel(const float* __restrict__ x,
                                                  const float* __restrict__ Wgk1,
                                                  float* __restrict__ xg1) {
  int gid = blockIdx.x * 256 + threadIdx.x;
  int m = gid >> 4, j = gid & 15;
  const float* xr = x + (size_t)m * H_;
  float s = 0.f;
  for (int k = 0; k < H_; ++k) s = fmaf(xr[k], Wgk1[k * LR_ + j], s);
  xg1[gid] = s;
}

// ---------------------------------------------------------------------------
__global__ __launch_bounds__(256) void gk_kernel(const float* __restrict__ xg1,
                                                 const float* __restrict__ Wgk2,
                                                 const float* __restrict__ bgk2,
                                                 float* __restrict__ gk) {
  int gid = blockIdx.x * 256 + threadIdx.x;
  int m = gid >> 9, n = gid & 511;
  const float* xr = xg1 + m * LR_;
  float s = bgk2[n];
#pragma unroll
  for (int r = 0; r < LR_; ++r) s = fmaf(xr[r], Wgk2[r * DK_ + n], s);
  float ls = fminf(s, 0.f) - log1pf(__expf(-fabsf(s)));
  gk[gid] = ls * (1.0f / 16.0f);
}

// ---------------------------------------------------------------------------
// Per-chunk prep: gcum prefix, Q~ = q*exp(gcum)*scale (in-place),
// Kinv = k*exp(-gcum) (in-place), KdecT[j][i] = k*exp(Gtot-gcum), D = exp(Gtot)
// grid = 128 units (bh*16 + c)
// ---------------------------------------------------------------------------
__global__ __launch_bounds__(256) void prep_kernel(const float* __restrict__ gk,
                                                   float* __restrict__ q,
                                                   float* __restrict__ k,
                                                   float* __restrict__ kdecT,
                                                   float* __restrict__ D) {
  __shared__ float gc[CHUNK][128];
  int unit = blockIdx.x;
  int c = unit & 15, bh = unit >> 4;
  int b = bh >> 2, h = bh & 3;
  int tid = threadIdx.x;
  size_t base = ((size_t)(b * T_ + c * CHUNK)) * DK_ + h * 128;
  if (tid < 128) {
    float g = 0.f;
    for (int i = 0; i < CHUNK; ++i) {
      g += gk[base + (size_t)i * DK_ + tid];
      gc[i][tid] = g;
    }
    D[unit * 128 + tid] = __expf(g);
  }
  __syncthreads();
  const float scale = 0.08838834764831845f;
#pragma unroll
  for (int e = 0; e < 32; ++e) {
    int idx = e * 256 + tid;
    int i = idx >> 7, j = idx & 127;
    float gv = gc[i][j];
    float G  = gc[CHUNK - 1][j];
    size_t off = base + (size_t)i * DK_ + j;
    float qv = q[off], kv = k[off];
    q[off] = qv * __expf(gv) * scale;
    k[off] = kv * __expf(-gv);
    kdecT[(size_t)unit * 8192 + j * CHUNK + i] = kv * __expf(G - gv);
  }
}

// ---------------------------------------------------------------------------
// U_c = KdecT[128,64] @ V_c[64,256]  -> states[c+1]
// grid: x = 8 tiles (mt*4+nt), y = c (0..14), z = bh
// ---------------------------------------------------------------------------
__global__ __launch_bounds__(256) void state_kernel(const float* __restrict__ kdecT,
                                                    const float* __restrict__ v,
                                                    float* __restrict__ states) {
  __shared__ float As[16][65];
  __shared__ float Bs[16][64];
  int tile = blockIdx.x;
  int mt = tile >> 2, nt = tile & 3;
  int c = blockIdx.y, bh = blockIdx.z;
  int b = bh >> 2, h = bh & 3;
  int tid = threadIdx.x;
  int tx4 = (tid & 15) << 2, ty4 = (tid >> 4) << 2;
  float acc[4][4] = {{0.f}};
  int ar = tid >> 2, ac = (tid & 3) << 2;
  int bk = tid >> 4, bc = (tid & 15) << 2;

  const float* Abase = kdecT + (size_t)(bh * 16 + c) * 8192 + (size_t)mt * 64 * 64;
  const float* Bbase = v + ((size_t)(b * T_ + c * CHUNK)) * DV_ + h * 256 + nt * 64;
  float* Cbase = states + ((size_t)(c + 1) * NBH + bh) * 32768 + (size_t)mt * 64 * 256 + nt * 64;

  for (int k0 = 0; k0 < 64; k0 += 16) {
    float4 a4 = *(const float4*)&Abase[(size_t)ar * 64 + k0 + ac];
    float4 b4 = *(const float4*)&Bbase[(size_t)(k0 + bk) * DV_ + bc];
    __syncthreads();
    As[ac + 0][ar] = a4.x;
    As[ac + 1][ar] = a4.y;
    As[ac + 2][ar] = a4.z;
    As[ac + 3][ar] = a4.w;
    *(float4*)&Bs[bk][bc] = b4;
    __syncthreads();
#pragma unroll
    for (int kk = 0; kk < 16; ++kk) {
      float av[4];
      av[0] = As[kk][ty4 + 0];
      av[1] = As[kk][ty4 + 1];
      av[2] = As[kk][ty4 + 2];
      av[3] = As[kk][ty4 + 3];
      float4 bq = *(const float4*)&Bs[kk][tx4];
      float bv[4] = {bq.x, bq.y, bq.z, bq.w};
#pragma unroll
      for (int i = 0; i < 4; ++i)
#pragma unroll
        for (int j = 0; j < 4; ++j)
          acc[i][j] = fmaf(av[i], bv[j], acc[i][j]);
    }
  }
#pragma unroll
  for (int i = 0; i < 4; ++i) {
    float4 o = make_float4(acc[i][0], acc[i][1], acc[i][2], acc[i][3]);
    *(float4*)&Cbase[(size_t)(ty4 + i) * 256 + tx4] = o;
  }
}

// ---------------------------------------------------------------------------
// Sequential chunk combine: states[c+1] = D_c * states[c] + U_{c} (in slot c+1)
// 262144 cells, 15 steps carried in registers.
// ---------------------------------------------------------------------------
__global__ __launch_bounds__(256) void combine_kernel(const float* __restrict__ D,
                                                      float* __restrict__ states) {
  int cell = blockIdx.x * 256 + threadIdx.x;
  int bh = cell >> 15;
  int r  = cell & 32767;
  int kk = r >> 8;
  float S = 0.f;
  for (int c = 0; c < 15; ++c) {
    float d = D[(bh * 16 + c) * 128 + kk];
    size_t off = ((size_t)(c + 1) * NBH + bh) * 32768 + r;
    S = fmaf(d, S, states[off]);
    states[off] = S;
  }
}

// ---------------------------------------------------------------------------
// A = mask_lower(Q~ @ Kinv^T), 64x64, K=128, per unit. grid = 128.
// ---------------------------------------------------------------------------
__global__ __launch_bounds__(256) void attn_kernel(const float* __restrict__ qt,
                                                   const float* __restrict__ kinv,
                                                   float* __restrict__ Amat) {
  __shared__ float As[16][65];
  __shared__ float Bs[16][65];
  int unit = blockIdx.x;
  int c = unit & 15, bh = unit >> 4;
  int b = bh >> 2, h = bh & 3;
  int tid = threadIdx.x;
  int tx4 = (tid & 15) << 2, ty4 = (tid >> 4) << 2;
  float acc[4][4] = {{0.f}};
  int ar = tid >> 2, ac = (tid & 3) << 2;

  size_t base = ((size_t)(b * T_ + c * CHUNK)) * DK_ + h * 128;

  for (int k0 = 0; k0 < 128; k0 += 16) {
    float4 a4 = *(const float4*)&qt[base + (size_t)ar * DK_ + k0 + ac];
    float4 b4 = *(const float4*)&kinv[base + (size_t)ar * DK_ + k0 + ac];
    __syncthreads();
    As[ac + 0][ar] = a4.x;
    As[ac + 1][ar] = a4.y;
    As[ac + 2][ar] = a4.z;
    As[ac + 3][ar] = a4.w;
    Bs[ac + 0][ar] = b4.x;
    Bs[ac + 1][ar] = b4.y;
    Bs[ac + 2][ar] = b4.z;
    Bs[ac + 3][ar] = b4.w;
    __syncthreads();
#pragma unroll
    for (int kk = 0; kk < 16; ++kk) {
      float av[4], bv[4];
#pragma unroll
      for (int i = 0; i < 4; ++i) av[i] = As[kk][ty4 + i];
#pragma unroll
      for (int j = 0; j < 4; ++j) bv[j] = Bs[kk][tx4 + j];
#pragma unroll
      for (int i = 0; i < 4; ++i)
#pragma unroll
        for (int j = 0; j < 4; ++j)
          acc[i][j] = fmaf(av[i], bv[j], acc[i][j]);
    }
  }
  size_t ab = (size_t)unit * 4096;
#pragma unroll
  for (int i = 0; i < 4; ++i)
#pragma unroll
    for (int j = 0; j < 4; ++j) {
      int row = ty4 + i, col = tx4 + j;
      Amat[ab + row * 64 + col] = (col <= row) ? acc[i][j] : 0.f;
    }
}

// ---------------------------------------------------------------------------
// O = A @ V_c + Q~ @ states[c].  grid: x=vt(4), y=c(16), z=bh(8)
// ---------------------------------------------------------------------------
__global__ __launch_bounds__(256) void out_kernel(const float* __restrict__ Amat,
                                                  const float* __restrict__ v,
                                                  const float* __restrict__ qt,
                                                  const float* __restrict__ states,
                                                  float* __restrict__ oraw) {
  __shared__ float As[16][65];
  __shared__ float Bs[16][64];
  int vt = blockIdx.x;
  int c  = blockIdx.y;
  int bh = blockIdx.z;
  int b = bh >> 2, h = bh & 3;
  int unit = bh * 16 + c;
  int tid = threadIdx.x;
  int tx4 = (tid & 15) << 2, ty4 = (tid >> 4) << 2;
  float acc[4][4] = {{0.f}};
  int ar = tid >> 2, ac = (tid & 3) << 2;
  int bk = tid >> 4, bc = (tid & 15) << 2;

  const float* Abase = Amat + (size_t)unit * 4096;
  const float* Vbase = v + ((size_t)(b * T_ + c * CHUNK)) * DV_ + h * 256 + vt * 64;
  const float* Qbase = qt + ((size_t)(b * T_ + c * CHUNK)) * DK_ + h * 128;
  const float* Sbase = states + ((size_t)c * NBH + bh) * 32768 + vt * 64;

  // phase A: += A[64x64] @ V[64x64]
  for (int k0 = 0; k0 < 64; k0 += 16) {
    float4 a4 = *(const float4*)&Abase[(size_t)ar * 64 + k0 + ac];
    float4 b4 = *(const float4*)&Vbase[(size_t)(k0 + bk) * DV_ + bc];
    __syncthreads();
    As[ac + 0][ar] = a4.x;
    As[ac + 1][ar] = a4.y;
    As[ac + 2][ar] = a4.z;
    As[ac + 3][ar] = a4.w;
    *(float4*)&Bs[bk][bc] = b4;
    __syncthreads();
#pragma unroll
    for (int kk = 0; kk < 16; ++kk) {
      float av[4];
#pragma unroll
      for (int i = 0; i < 4; ++i) av[i] = As[kk][ty4 + i];
      float4 bq = *(const float4*)&Bs[kk][tx4];
      float bv[4] = {bq.x, bq.y, bq.z, bq.w};
#pragma unroll
      for (int i = 0; i < 4; ++i)
#pragma unroll
        for (int j = 0; j < 4; ++j)
          acc[i][j] = fmaf(av[i], bv[j], acc[i][j]);
    }
  }
  // phase B: += Q~[64x128] @ S[128x64]
  for (int k0 = 0; k0 < 128; k0 += 16) {
    float4 a4 = *(const float4*)&Qbase[(size_t)ar * DK_ + k0 + ac];
    float4 b4 = *(const float4*)&Sbase[(size_t)(k0 + bk) * 256 + bc];
    __syncthreads();
    As[ac + 0][ar] = a4.x;
    As[ac + 1][ar] = a4.y;
    As[ac + 2][ar] = a4.z;
    As[ac + 3][ar] = a4.w;
    *(float4*)&Bs[bk][bc] = b4;
    __syncthreads();
#pragma unroll
    for (int kk = 0; kk < 16; ++kk) {
      float av[4];
#pragma unroll
      for (int i = 0; i < 4; ++i) av[i] = As[kk][ty4 + i];
      float4 bq = *(const float4*)&Bs[kk][tx4];
      float bv[4] = {bq.x, bq.y, bq.z, bq.w};
#pragma unroll
      for (int i = 0; i < 4; ++i)
#pragma unroll
        for (int j = 0; j < 4; ++j)
          acc[i][j] = fmaf(av[i], bv[j], acc[i][j]);
    }
  }
#pragma unroll
  for (int i = 0; i < 4; ++i) {
    float4 o = make_float4(acc[i][0], acc[i][1], acc[i][2], acc[i][3]);
    *(float4*)&oraw[((size_t)(b * T_ + c * CHUNK) + ty4 + i) * DV_ + h * 256 + vt * 64 + tx4] = o;
  }
}

// ---------------------------------------------------------------------------
// Fused RMSNorm * gw * swish(g), in-place on oraw.
// ---------------------------------------------------------------------------
__global__ __launch_bounds__(256) void norm_gate(float* __restrict__ Oraw,
                                                 const float* __restrict__ G,
                                                 const float* __restrict__ gw,
                                                 float* __restrict__ On) {
  int row = blockIdx.x;
  int j = threadIdx.x;
  size_t idx = (size_t)row * 256 + j;
  float o = Oraw[idx];
  float ss = o * o;
#pragma unroll
  for (int off = 32; off > 0; off >>= 1) ss += __shfl_xor(ss, off);
  __shared__ float red[4];
  if ((j & 63) == 0) red[j >> 6] = ss;
  __syncthreads();
  float tot = (red[0] + red[1]) + (red[2] + red[3]);
  float r = rsqrtf(tot * (1.0f / 256.0f) + 1e-5f);
  float gval = G[idx];
  float sw = gval / (1.0f + __expf(-gval));
  On[idx] = o * r * gw[j] * sw;
}

// ---------------------------------------------------------------------------
extern "C" void kernel_launch(void* const* d_in, const int* in_sizes, int n_in,
                              void* d_out, int out_size, void* d_ws, size_t ws_size,
                              hipStream_t stream) {
  const float* x    = (const float*)d_in[0];
  const float* Wq   = (const float*)d_in[1];
  const float* Wk   = (const float*)d_in[2];
  const float* Wv   = (const float*)d_in[3];
  const float* Wgk1 = (const float*)d_in[4];
  const float* Wgk2 = (const float*)d_in[5];
  const float* bgk2 = (const float*)d_in[6];
  const float* Wg   = (const float*)d_in[7];
  const float* Wo   = (const float*)d_in[8];
  const float* gw   = (const float*)d_in[9];
  float* out = (float*)d_out;

  const size_t M = 2048;
  float* ws     = (float*)d_ws;
  float* q      = ws;                   // 2048*512   (becomes Q~)
  float* k      = q      + M * 512;     // 2048*512   (becomes Kinv)
  float* v      = k      + M * 512;     // 2048*1024
  float* g      = v      + M * 1024;    // 2048*1024
  float* xg1    = g      + M * 1024;    // 2048*16
  float* gk     = xg1    + M * 16;      // 2048*512
  float* oraw   = gk     + M * 512;     // 2048*1024
  float* kdecT  = oraw   + M * 1024;    // 128*8192 = 1048576
  float* Amat   = kdecT  + 1048576;     // 128*4096 = 524288
  float* D      = Amat   + 524288;      // 128*128  = 16384
  float* states = D      + 16384;       // 16*8*32768 = 4194304

  dim3 blk(256);
  gemm_f32<<<dim3(DK_ / 64, M / 64), blk, 0, stream>>>(x, Wq, q, M, DK_, H_);
  gemm_f32<<<dim3(DK_ / 64, M / 64), blk, 0, stream>>>(x, Wk, k, M, DK_, H_);
  gemm_f32<<<dim3(DV_ / 64, M / 64), blk, 0, stream>>>(x, Wv, v, M, DV_, H_);
  gemm_f32<<<dim3(DV_ / 64, M / 64), blk, 0, stream>>>(x, Wg, g, M, DV_, H_);
  lr1_kernel<<<(M * 16) / 256, blk, 0, stream>>>(x, Wgk1, xg1);
  gk_kernel<<<(M * DK_) / 256, blk, 0, stream>>>(xg1, Wgk2, bgk2, gk);

  prep_kernel<<<128, blk, 0, stream>>>(gk, q, k, kdecT, D);
  hipMemsetAsync(states, 0, (size_t)NBH * 32768 * 4, stream);  // slot 0 = S_0 = 0
  state_kernel<<<dim3(8, 15, 8), blk, 0, stream>>>(kdecT, v, states);
  combine_kernel<<<1024, blk, 0, stream>>>(D, states);
  attn_kernel<<<128, blk, 0, stream>>>(q, k, Amat);
  out_kernel<<<dim3(4, 16, 8), blk, 0, stream>>>(Amat, v, q, states, oraw);

  norm_gate<<<M * 4, blk, 0, stream>>>(oraw, g, gw, oraw);
  gemm_f32<<<dim3(H_ / 64, M / 64), blk, 0, stream>>>(oraw, Wo, out, M, H_, DV_);
}

// Round 3
// 193.237 us; speedup vs baseline: 5.2510x; 2.2813x over previous
//
#include <hip/hip_runtime.h>
#include <math.h>

#define T_  1024
#define H_  1024
#define DK_ 512
#define DV_ 1024
#define LR_ 16
#define CHUNK 64
#define NC 16
#define NBH 8

using f32x4  = __attribute__((ext_vector_type(4))) float;
using bf16x8 = __attribute__((ext_vector_type(8))) short;   // 8 bf16 in 4 VGPRs
using u16x4  = __attribute__((ext_vector_type(4))) unsigned short;

__device__ __forceinline__ unsigned short f2bf(float f) {
  union { float f; unsigned int u; } v; v.f = f;
  unsigned int r = v.u + 0x7FFF + ((v.u >> 16) & 1);   // round-to-nearest-even
  return (unsigned short)(r >> 16);
}

__device__ __forceinline__ void gll16(const void* g, void* l) {
  __builtin_amdgcn_global_load_lds((const __attribute__((address_space(1))) void*)g,
                                   (__attribute__((address_space(3))) void*)l, 16, 0, 0);
}

// ---------------------------------------------------------------------------
// bf16 MFMA GEMM: C[M,N] f32 = A[M,K] bf16 @ Bt[N,K] bf16 (B transposed).
// 64x64 tile, BK=64, 256 thr = 4 waves, each wave 32x32 (2x2 16x16 frags).
// LDS row-major [64][64] bf16 with chunk-XOR swizzle (chunk ^= row&7) applied
// on BOTH the global_load_lds source address and the ds_read address.
// ---------------------------------------------------------------------------
__global__ __launch_bounds__(256) void gemm_bf16(const unsigned short* __restrict__ A,
                                                 const unsigned short* __restrict__ Bt,
                                                 float* __restrict__ C,
                                                 int M, int N, int K) {
  __shared__ short Asm[4096];   // 64 rows x 64 bf16 = 8 KB
  __shared__ short Bsm[4096];
  int tid = threadIdx.x;
  int w = tid >> 6, l = tid & 63;
  int bm = blockIdx.y << 6, bn = blockIdx.x << 6;

  // staging: issue i covers rows i*32 + w*8 + (l>>3); slot s=l&7 holds global
  // chunk s ^ (row&7); row&7 == l>>3 here, so source chunk = (l&7)^(l>>3).
  int srow = (w << 3) + (l >> 3);
  int schunk = ((l & 7) ^ (l >> 3)) << 3;           // element offset in k
  const unsigned short* pA0 = A  + (size_t)(bm + srow) * K + schunk;
  const unsigned short* pA1 = A  + (size_t)(bm + 32 + srow) * K + schunk;
  const unsigned short* pB0 = Bt + (size_t)(bn + srow) * K + schunk;
  const unsigned short* pB1 = Bt + (size_t)(bn + 32 + srow) * K + schunk;
  char* AsmB = (char*)Asm;
  char* BsmB = (char*)Bsm;
  int ldsw = w << 10;                                // wave-uniform byte base

  // fragment read offsets (element units)
  int ro = (w >> 1) << 5, co = (w & 1) << 5;
  int lrow = l & 15, g4 = l >> 4, lx = l & 7;
  int aidx[2][2], bidx[2][2];
#pragma unroll
  for (int mi = 0; mi < 2; ++mi)
#pragma unroll
    for (int ks = 0; ks < 2; ++ks) {
      aidx[mi][ks] = (ro + mi * 16 + lrow) * 64 + ((((ks << 2) + g4) ^ lx) << 3);
      bidx[mi][ks] = (co + mi * 16 + lrow) * 64 + ((((ks << 2) + g4) ^ lx) << 3);
    }

  f32x4 acc[2][2] = {};

  for (int k0 = 0; k0 < K; k0 += 64) {
    gll16(pA0 + k0, AsmB + ldsw);
    gll16(pA1 + k0, AsmB + 4096 + ldsw);
    gll16(pB0 + k0, BsmB + ldsw);
    gll16(pB1 + k0, BsmB + 4096 + ldsw);
    __syncthreads();                                  // drains vmcnt
    bf16x8 a[2][2], b[2][2];
#pragma unroll
    for (int mi = 0; mi < 2; ++mi)
#pragma unroll
      for (int ks = 0; ks < 2; ++ks) {
        a[mi][ks] = *(const bf16x8*)(Asm + aidx[mi][ks]);
        b[mi][ks] = *(const bf16x8*)(Bsm + bidx[mi][ks]);
      }
#pragma unroll
    for (int mi = 0; mi < 2; ++mi)
#pragma unroll
      for (int ni = 0; ni < 2; ++ni)
#pragma unroll
        for (int ks = 0; ks < 2; ++ks)
          acc[mi][ni] = __builtin_amdgcn_mfma_f32_16x16x32_bf16(
              a[mi][ks], b[ni][ks], acc[mi][ni], 0, 0, 0);
    __syncthreads();                                  // all waves done reading
  }

#pragma unroll
  for (int mi = 0; mi < 2; ++mi)
#pragma unroll
    for (int ni = 0; ni < 2; ++ni) {
      int row0 = bm + ro + mi * 16 + (g4 << 2);
      int col  = bn + co + ni * 16 + lrow;
#pragma unroll
      for (int j = 0; j < 4; ++j)
        C[(size_t)(row0 + j) * N + col] = acc[mi][ni][j];
    }
}

// ---------------------------------------------------------------------------
// f32 -> bf16 elementwise (4 per thread)
// ---------------------------------------------------------------------------
__global__ __launch_bounds__(256) void conv_x(const float* __restrict__ in,
                                              unsigned short* __restrict__ out) {
  int i = (blockIdx.x * 256 + threadIdx.x) << 2;
  float4 v = *(const float4*)&in[i];
  u16x4 o = {f2bf(v.x), f2bf(v.y), f2bf(v.z), f2bf(v.w)};
  *(u16x4*)&out[i] = o;
}

// ---------------------------------------------------------------------------
// out[c][r] = bf16(in[r][c]); in [R][C] f32. grid (C/32, R/32), 256 thr.
// ---------------------------------------------------------------------------
__global__ __launch_bounds__(256) void transpose_bf16(const float* __restrict__ in,
                                                      unsigned short* __restrict__ out,
                                                      int R, int C) {
  __shared__ float tile[32][33];
  int bx = blockIdx.x << 5, by = blockIdx.y << 5;
  int tx = threadIdx.x & 31, ty = threadIdx.x >> 5;
#pragma unroll
  for (int i = 0; i < 32; i += 8)
    tile[ty + i][tx] = in[(size_t)(by + ty + i) * C + bx + tx];
  __syncthreads();
#pragma unroll
  for (int i = 0; i < 32; i += 8)
    out[(size_t)(bx + ty + i) * R + by + tx] = f2bf(tile[tx][ty + i]);
}

// ---------------------------------------------------------------------------
__global__ __launch_bounds__(256) void lr1_kernel(const float* __restrict__ x,
                                                  const float* __restrict__ Wgk1,
                                                  float* __restrict__ xg1) {
  int gid = blockIdx.x * 256 + threadIdx.x;
  int m = gid >> 4, j = gid & 15;
  const float* xr = x + (size_t)m * H_;
  float s = 0.f;
  for (int k = 0; k < H_; ++k) s = fmaf(xr[k], Wgk1[k * LR_ + j], s);
  xg1[gid] = s;
}

// ---------------------------------------------------------------------------
__global__ __launch_bounds__(256) void gk_kernel(const float* __restrict__ xg1,
                                                 const float* __restrict__ Wgk2,
                                                 const float* __restrict__ bgk2,
                                                 float* __restrict__ gk) {
  int gid = blockIdx.x * 256 + threadIdx.x;
  int m = gid >> 9, n = gid & 511;
  const float* xr = xg1 + m * LR_;
  float s = bgk2[n];
#pragma unroll
  for (int r = 0; r < LR_; ++r) s = fmaf(xr[r], Wgk2[r * DK_ + n], s);
  float ls = fminf(s, 0.f) - log1pf(__expf(-fabsf(s)));
  gk[gid] = ls * (1.0f / 16.0f);
}

// ---------------------------------------------------------------------------
__global__ __launch_bounds__(256) void prep_kernel(const float* __restrict__ gk,
                                                   float* __restrict__ q,
                                                   float* __restrict__ k,
                                                   float* __restrict__ kdecT,
                                                   float* __restrict__ D) {
  __shared__ float gc[CHUNK][128];
  int unit = blockIdx.x;
  int c = unit & 15, bh = unit >> 4;
  int b = bh >> 2, h = bh & 3;
  int tid = threadIdx.x;
  size_t base = ((size_t)(b * T_ + c * CHUNK)) * DK_ + h * 128;
  if (tid < 128) {
    float g = 0.f;
    for (int i = 0; i < CHUNK; ++i) {
      g += gk[base + (size_t)i * DK_ + tid];
      gc[i][tid] = g;
    }
    D[unit * 128 + tid] = __expf(g);
  }
  __syncthreads();
  const float scale = 0.08838834764831845f;
#pragma unroll
  for (int e = 0; e < 32; ++e) {
    int idx = e * 256 + tid;
    int i = idx >> 7, j = idx & 127;
    float gv = gc[i][j];
    float G  = gc[CHUNK - 1][j];
    size_t off = base + (size_t)i * DK_ + j;
    float qv = q[off], kv = k[off];
    q[off] = qv * __expf(gv) * scale;
    k[off] = kv * __expf(-gv);
    kdecT[(size_t)unit * 8192 + j * CHUNK + i] = kv * __expf(G - gv);
  }
}

// ---------------------------------------------------------------------------
__global__ __launch_bounds__(256) void state_kernel(const float* __restrict__ kdecT,
                                                    const float* __restrict__ v,
                                                    float* __restrict__ states) {
  __shared__ float As[16][65];
  __shared__ float Bs[16][64];
  int tile = blockIdx.x;
  int mt = tile >> 2, nt = tile & 3;
  int c = blockIdx.y, bh = blockIdx.z;
  int b = bh >> 2, h = bh & 3;
  int tid = threadIdx.x;
  int tx4 = (tid & 15) << 2, ty4 = (tid >> 4) << 2;
  float acc[4][4] = {{0.f}};
  int ar = tid >> 2, ac = (tid & 3) << 2;
  int bk = tid >> 4, bc = (tid & 15) << 2;

  const float* Abase = kdecT + (size_t)(bh * 16 + c) * 8192 + (size_t)mt * 64 * 64;
  const float* Bbase = v + ((size_t)(b * T_ + c * CHUNK)) * DV_ + h * 256 + nt * 64;
  float* Cbase = states + ((size_t)(c + 1) * NBH + bh) * 32768 + (size_t)mt * 64 * 256 + nt * 64;

  for (int k0 = 0; k0 < 64; k0 += 16) {
    float4 a4 = *(const float4*)&Abase[(size_t)ar * 64 + k0 + ac];
    float4 b4 = *(const float4*)&Bbase[(size_t)(k0 + bk) * DV_ + bc];
    __syncthreads();
    As[ac + 0][ar] = a4.x;
    As[ac + 1][ar] = a4.y;
    As[ac + 2][ar] = a4.z;
    As[ac + 3][ar] = a4.w;
    *(float4*)&Bs[bk][bc] = b4;
    __syncthreads();
#pragma unroll
    for (int kk = 0; kk < 16; ++kk) {
      float av[4];
      av[0] = As[kk][ty4 + 0];
      av[1] = As[kk][ty4 + 1];
      av[2] = As[kk][ty4 + 2];
      av[3] = As[kk][ty4 + 3];
      float4 bq = *(const float4*)&Bs[kk][tx4];
      float bv[4] = {bq.x, bq.y, bq.z, bq.w};
#pragma unroll
      for (int i = 0; i < 4; ++i)
#pragma unroll
        for (int j = 0; j < 4; ++j)
          acc[i][j] = fmaf(av[i], bv[j], acc[i][j]);
    }
  }
#pragma unroll
  for (int i = 0; i < 4; ++i) {
    float4 o = make_float4(acc[i][0], acc[i][1], acc[i][2], acc[i][3]);
    *(float4*)&Cbase[(size_t)(ty4 + i) * 256 + tx4] = o;
  }
}

// ---------------------------------------------------------------------------
__global__ __launch_bounds__(256) void combine_kernel(const float* __restrict__ D,
                                                      float* __restrict__ states) {
  int cell = blockIdx.x * 256 + threadIdx.x;
  int bh = cell >> 15;
  int r  = cell & 32767;
  int kk = r >> 8;
  float S = 0.f;
  for (int c = 0; c < 15; ++c) {
    float d = D[(bh * 16 + c) * 128 + kk];
    size_t off = ((size_t)(c + 1) * NBH + bh) * 32768 + r;
    S = fmaf(d, S, states[off]);
    states[off] = S;
  }
}

// ---------------------------------------------------------------------------
__global__ __launch_bounds__(256) void attn_kernel(const float* __restrict__ qt,
                                                   const float* __restrict__ kinv,
                                                   float* __restrict__ Amat) {
  __shared__ float As[16][65];
  __shared__ float Bs[16][65];
  int unit = blockIdx.x;
  int c = unit & 15, bh = unit >> 4;
  int b = bh >> 2, h = bh & 3;
  int tid = threadIdx.x;
  int tx4 = (tid & 15) << 2, ty4 = (tid >> 4) << 2;
  float acc[4][4] = {{0.f}};
  int ar = tid >> 2, ac = (tid & 3) << 2;

  size_t base = ((size_t)(b * T_ + c * CHUNK)) * DK_ + h * 128;

  for (int k0 = 0; k0 < 128; k0 += 16) {
    float4 a4 = *(const float4*)&qt[base + (size_t)ar * DK_ + k0 + ac];
    float4 b4 = *(const float4*)&kinv[base + (size_t)ar * DK_ + k0 + ac];
    __syncthreads();
    As[ac + 0][ar] = a4.x;
    As[ac + 1][ar] = a4.y;
    As[ac + 2][ar] = a4.z;
    As[ac + 3][ar] = a4.w;
    Bs[ac + 0][ar] = b4.x;
    Bs[ac + 1][ar] = b4.y;
    Bs[ac + 2][ar] = b4.z;
    Bs[ac + 3][ar] = b4.w;
    __syncthreads();
#pragma unroll
    for (int kk = 0; kk < 16; ++kk) {
      float av[4], bv[4];
#pragma unroll
      for (int i = 0; i < 4; ++i) av[i] = As[kk][ty4 + i];
#pragma unroll
      for (int j = 0; j < 4; ++j) bv[j] = Bs[kk][tx4 + j];
#pragma unroll
      for (int i = 0; i < 4; ++i)
#pragma unroll
        for (int j = 0; j < 4; ++j)
          acc[i][j] = fmaf(av[i], bv[j], acc[i][j]);
    }
  }
  size_t ab = (size_t)unit * 4096;
#pragma unroll
  for (int i = 0; i < 4; ++i)
#pragma unroll
    for (int j = 0; j < 4; ++j) {
      int row = ty4 + i, col = tx4 + j;
      Amat[ab + row * 64 + col] = (col <= row) ? acc[i][j] : 0.f;
    }
}

// ---------------------------------------------------------------------------
__global__ __launch_bounds__(256) void out_kernel(const float* __restrict__ Amat,
                                                  const float* __restrict__ v,
                                                  const float* __restrict__ qt,
                                                  const float* __restrict__ states,
                                                  float* __restrict__ oraw) {
  __shared__ float As[16][65];
  __shared__ float Bs[16][64];
  int vt = blockIdx.x;
  int c  = blockIdx.y;
  int bh = blockIdx.z;
  int b = bh >> 2, h = bh & 3;
  int unit = bh * 16 + c;
  int tid = threadIdx.x;
  int tx4 = (tid & 15) << 2, ty4 = (tid >> 4) << 2;
  float acc[4][4] = {{0.f}};
  int ar = tid >> 2, ac = (tid & 3) << 2;
  int bk = tid >> 4, bc = (tid & 15) << 2;

  const float* Abase = Amat + (size_t)unit * 4096;
  const float* Vbase = v + ((size_t)(b * T_ + c * CHUNK)) * DV_ + h * 256 + vt * 64;
  const float* Qbase = qt + ((size_t)(b * T_ + c * CHUNK)) * DK_ + h * 128;
  const float* Sbase = states + ((size_t)c * NBH + bh) * 32768 + vt * 64;

  for (int k0 = 0; k0 < 64; k0 += 16) {
    float4 a4 = *(const float4*)&Abase[(size_t)ar * 64 + k0 + ac];
    float4 b4 = *(const float4*)&Vbase[(size_t)(k0 + bk) * DV_ + bc];
    __syncthreads();
    As[ac + 0][ar] = a4.x;
    As[ac + 1][ar] = a4.y;
    As[ac + 2][ar] = a4.z;
    As[ac + 3][ar] = a4.w;
    *(float4*)&Bs[bk][bc] = b4;
    __syncthreads();
#pragma unroll
    for (int kk = 0; kk < 16; ++kk) {
      float av[4];
#pragma unroll
      for (int i = 0; i < 4; ++i) av[i] = As[kk][ty4 + i];
      float4 bq = *(const float4*)&Bs[kk][tx4];
      float bv[4] = {bq.x, bq.y, bq.z, bq.w};
#pragma unroll
      for (int i = 0; i < 4; ++i)
#pragma unroll
        for (int j = 0; j < 4; ++j)
          acc[i][j] = fmaf(av[i], bv[j], acc[i][j]);
    }
  }
  for (int k0 = 0; k0 < 128; k0 += 16) {
    float4 a4 = *(const float4*)&Qbase[(size_t)ar * DK_ + k0 + ac];
    float4 b4 = *(const float4*)&Sbase[(size_t)(k0 + bk) * 256 + bc];
    __syncthreads();
    As[ac + 0][ar] = a4.x;
    As[ac + 1][ar] = a4.y;
    As[ac + 2][ar] = a4.z;
    As[ac + 3][ar] = a4.w;
    *(float4*)&Bs[bk][bc] = b4;
    __syncthreads();
#pragma unroll
    for (int kk = 0; kk < 16; ++kk) {
      float av[4];
#pragma unroll
      for (int i = 0; i < 4; ++i) av[i] = As[kk][ty4 + i];
      float4 bq = *(const float4*)&Bs[kk][tx4];
      float bv[4] = {bq.x, bq.y, bq.z, bq.w};
#pragma unroll
      for (int i = 0; i < 4; ++i)
#pragma unroll
        for (int j = 0; j < 4; ++j)
          acc[i][j] = fmaf(av[i], bv[j], acc[i][j]);
    }
  }
#pragma unroll
  for (int i = 0; i < 4; ++i) {
    float4 o = make_float4(acc[i][0], acc[i][1], acc[i][2], acc[i][3]);
    *(float4*)&oraw[((size_t)(b * T_ + c * CHUNK) + ty4 + i) * DV_ + h * 256 + vt * 64 + tx4] = o;
  }
}

// ---------------------------------------------------------------------------
// Fused RMSNorm * gw * swish(g). Emits bf16 (feeds the final MFMA GEMM).
// ---------------------------------------------------------------------------
__global__ __launch_bounds__(256) void norm_gate(const float* __restrict__ Oraw,
                                                 const float* __restrict__ G,
                                                 const float* __restrict__ gw,
                                                 unsigned short* __restrict__ On) {
  int row = blockIdx.x;
  int j = threadIdx.x;
  size_t idx = (size_t)row * 256 + j;
  float o = Oraw[idx];
  float ss = o * o;
#pragma unroll
  for (int off = 32; off > 0; off >>= 1) ss += __shfl_xor(ss, off);
  __shared__ float red[4];
  if ((j & 63) == 0) red[j >> 6] = ss;
  __syncthreads();
  float tot = (red[0] + red[1]) + (red[2] + red[3]);
  float r = rsqrtf(tot * (1.0f / 256.0f) + 1e-5f);
  float gval = G[idx];
  float sw = gval / (1.0f + __expf(-gval));
  On[idx] = f2bf(o * r * gw[j] * sw);
}

// ---------------------------------------------------------------------------
extern "C" void kernel_launch(void* const* d_in, const int* in_sizes, int n_in,
                              void* d_out, int out_size, void* d_ws, size_t ws_size,
                              hipStream_t stream) {
  const float* x    = (const float*)d_in[0];
  const float* Wq   = (const float*)d_in[1];
  const float* Wk   = (const float*)d_in[2];
  const float* Wv   = (const float*)d_in[3];
  const float* Wgk1 = (const float*)d_in[4];
  const float* Wgk2 = (const float*)d_in[5];
  const float* bgk2 = (const float*)d_in[6];
  const float* Wg   = (const float*)d_in[7];
  const float* Wo   = (const float*)d_in[8];
  const float* gw   = (const float*)d_in[9];
  float* out = (float*)d_out;

  const size_t M = 2048;
  float* ws     = (float*)d_ws;
  float* q      = ws;                   // 1,048,576
  float* k      = q      + 1048576;     // 1,048,576
  float* v      = k      + 1048576;     // 2,097,152
  float* g      = v      + 2097152;     // 2,097,152
  float* xg1    = g      + 2097152;     //    32,768
  float* gk     = xg1    + 32768;       // 1,048,576
  float* oraw   = gk     + 1048576;     // 2,097,152
  float* kdecT  = oraw   + 2097152;     // 1,048,576
  float* Amat   = kdecT  + 1048576;     //   524,288
  float* D      = Amat   + 524288;      //    16,384
  float* states = D      + 16384;       // 4,194,304
  float* WotF   = states + 4194304;     //   524,288  (end: 15.78 M floats = 63.1 MB)

  // bf16 aliases: xb/W*t live only before memset(states); onb only after kdecT dies
  unsigned short* xb  = (unsigned short*)states;
  unsigned short* Wqt = (unsigned short*)(states + 1048576);
  unsigned short* Wkt = (unsigned short*)(states + 1310720);
  unsigned short* Wvt = (unsigned short*)(states + 1572864);
  unsigned short* Wgt = (unsigned short*)(states + 2097152);
  unsigned short* Wot = (unsigned short*)WotF;
  unsigned short* onb = (unsigned short*)kdecT;

  dim3 blk(256);
  conv_x<<<2048, blk, 0, stream>>>(x, xb);
  transpose_bf16<<<dim3(16, 32), blk, 0, stream>>>(Wq, Wqt, H_, DK_);
  transpose_bf16<<<dim3(16, 32), blk, 0, stream>>>(Wk, Wkt, H_, DK_);
  transpose_bf16<<<dim3(32, 32), blk, 0, stream>>>(Wv, Wvt, H_, DV_);
  transpose_bf16<<<dim3(32, 32), blk, 0, stream>>>(Wg, Wgt, H_, DV_);
  transpose_bf16<<<dim3(32, 32), blk, 0, stream>>>(Wo, Wot, DV_, H_);

  gemm_bf16<<<dim3(8, 32),  blk, 0, stream>>>(xb, Wqt, q, M, DK_, H_);
  gemm_bf16<<<dim3(8, 32),  blk, 0, stream>>>(xb, Wkt, k, M, DK_, H_);
  gemm_bf16<<<dim3(16, 32), blk, 0, stream>>>(xb, Wvt, v, M, DV_, H_);
  gemm_bf16<<<dim3(16, 32), blk, 0, stream>>>(xb, Wgt, g, M, DV_, H_);

  lr1_kernel<<<(M * 16) / 256, blk, 0, stream>>>(x, Wgk1, xg1);
  gk_kernel<<<(M * DK_) / 256, blk, 0, stream>>>(xg1, Wgk2, bgk2, gk);

  prep_kernel<<<128, blk, 0, stream>>>(gk, q, k, kdecT, D);
  hipMemsetAsync(states, 0, (size_t)NBH * 32768 * 4, stream);
  state_kernel<<<dim3(8, 15, 8), blk, 0, stream>>>(kdecT, v, states);
  combine_kernel<<<1024, blk, 0, stream>>>(D, states);
  attn_kernel<<<128, blk, 0, stream>>>(q, k, Amat);
  out_kernel<<<dim3(4, 16, 8), blk, 0, stream>>>(Amat, v, q, states, oraw);

  norm_gate<<<M * 4, blk, 0, stream>>>(oraw, g, gw, onb);
  gemm_bf16<<<dim3(16, 32), blk, 0, stream>>>(onb, Wot, out, M, H_, DV_);
}

// Round 4
// 129.662 us; speedup vs baseline: 7.8255x; 1.4903x over previous
//
#include <hip/hip_runtime.h>
#include <math.h>

#define T_  1024
#define H_  1024
#define DK_ 512
#define DV_ 1024
#define LR_ 16
#define CHUNK 64

using f32x4  = __attribute__((ext_vector_type(4))) float;
using bf16x8 = __attribute__((ext_vector_type(8))) short;
using u16x4  = __attribute__((ext_vector_type(4))) unsigned short;
typedef unsigned short u16;

__device__ __forceinline__ u16 f2bf(float f) {
  union { float f; unsigned int u; } v; v.f = f;
  unsigned int r = v.u + 0x7FFF + ((v.u >> 16) & 1);
  return (u16)(r >> 16);
}
__device__ __forceinline__ float bf2f(u16 u) {
  union { unsigned int i; float f; } v; v.i = ((unsigned int)u) << 16;
  return v.f;
}
__device__ __forceinline__ void gll16(const void* g, void* l) {
  __builtin_amdgcn_global_load_lds((const __attribute__((address_space(1))) void*)g,
                                   (__attribute__((address_space(3))) void*)l, 16, 0, 0);
}

// ---------------------------------------------------------------------------
// bf16 MFMA GEMM: C[M,N] = A[M,K] bf16 @ Bt[N,K] bf16. C fp32 or bf16.
// 64x64 tile, BK=64, 4 waves, chunk-XOR swizzle both sides.
// ---------------------------------------------------------------------------
template <bool OBF>
__global__ __launch_bounds__(256) void gemm_bf16_t(const u16* __restrict__ A,
                                                   const u16* __restrict__ Bt,
                                                   void* __restrict__ Cv,
                                                   int M, int N, int K) {
  __shared__ short Asm[4096];
  __shared__ short Bsm[4096];
  int tid = threadIdx.x;
  int w = tid >> 6, l = tid & 63;
  int bm = blockIdx.y << 6, bn = blockIdx.x << 6;

  int srow = (w << 3) + (l >> 3);
  int schunk = ((l & 7) ^ (l >> 3)) << 3;
  const u16* pA0 = A  + (size_t)(bm + srow) * K + schunk;
  const u16* pA1 = A  + (size_t)(bm + 32 + srow) * K + schunk;
  const u16* pB0 = Bt + (size_t)(bn + srow) * K + schunk;
  const u16* pB1 = Bt + (size_t)(bn + 32 + srow) * K + schunk;
  char* AsmB = (char*)Asm;
  char* BsmB = (char*)Bsm;
  int ldsw = w << 10;

  int ro = (w >> 1) << 5, co = (w & 1) << 5;
  int lrow = l & 15, g4 = l >> 4, lx = l & 7;
  int aidx[2][2], bidx[2][2];
#pragma unroll
  for (int mi = 0; mi < 2; ++mi)
#pragma unroll
    for (int ks = 0; ks < 2; ++ks) {
      aidx[mi][ks] = (ro + mi * 16 + lrow) * 64 + ((((ks << 2) + g4) ^ lx) << 3);
      bidx[mi][ks] = (co + mi * 16 + lrow) * 64 + ((((ks << 2) + g4) ^ lx) << 3);
    }

  f32x4 acc[2][2] = {};
  for (int k0 = 0; k0 < K; k0 += 64) {
    gll16(pA0 + k0, AsmB + ldsw);
    gll16(pA1 + k0, AsmB + 4096 + ldsw);
    gll16(pB0 + k0, BsmB + ldsw);
    gll16(pB1 + k0, BsmB + 4096 + ldsw);
    __syncthreads();
    bf16x8 a[2][2], b[2][2];
#pragma unroll
    for (int mi = 0; mi < 2; ++mi)
#pragma unroll
      for (int ks = 0; ks < 2; ++ks) {
        a[mi][ks] = *(const bf16x8*)(Asm + aidx[mi][ks]);
        b[mi][ks] = *(const bf16x8*)(Bsm + bidx[mi][ks]);
      }
#pragma unroll
    for (int mi = 0; mi < 2; ++mi)
#pragma unroll
      for (int ni = 0; ni < 2; ++ni)
#pragma unroll
        for (int ks = 0; ks < 2; ++ks)
          acc[mi][ni] = __builtin_amdgcn_mfma_f32_16x16x32_bf16(
              a[mi][ks], b[ni][ks], acc[mi][ni], 0, 0, 0);
    __syncthreads();
  }
#pragma unroll
  for (int mi = 0; mi < 2; ++mi)
#pragma unroll
    for (int ni = 0; ni < 2; ++ni) {
      int row0 = bm + ro + mi * 16 + (g4 << 2);
      int col  = bn + co + ni * 16 + lrow;
#pragma unroll
      for (int j = 0; j < 4; ++j) {
        if (OBF) ((u16*)Cv)[(size_t)(row0 + j) * N + col] = f2bf(acc[mi][ni][j]);
        else     ((float*)Cv)[(size_t)(row0 + j) * N + col] = acc[mi][ni][j];
      }
    }
}

// ---------------------------------------------------------------------------
__global__ __launch_bounds__(256) void conv_x(const float* __restrict__ in,
                                              u16* __restrict__ out) {
  int i = (blockIdx.x * 256 + threadIdx.x) << 2;
  float4 v = *(const float4*)&in[i];
  u16x4 o = {f2bf(v.x), f2bf(v.y), f2bf(v.z), f2bf(v.w)};
  *(u16x4*)&out[i] = o;
}

// out[c][r] = bf16(in[r][c]); in [R][C] f32.
__global__ __launch_bounds__(256) void transpose_bf16(const float* __restrict__ in,
                                                      u16* __restrict__ out,
                                                      int R, int C) {
  __shared__ float tile[32][33];
  int bx = blockIdx.x << 5, by = blockIdx.y << 5;
  int tx = threadIdx.x & 31, ty = threadIdx.x >> 5;
#pragma unroll
  for (int i = 0; i < 32; i += 8)
    tile[ty + i][tx] = in[(size_t)(by + ty + i) * C + bx + tx];
  __syncthreads();
#pragma unroll
  for (int i = 0; i < 32; i += 8)
    out[(size_t)(bx + ty + i) * R + by + tx] = f2bf(tile[tx][ty + i]);
}

// ---------------------------------------------------------------------------
__global__ __launch_bounds__(256) void lr1_kernel(const float* __restrict__ x,
                                                  const float* __restrict__ Wgk1,
                                                  float* __restrict__ xg1) {
  int gid = blockIdx.x * 256 + threadIdx.x;
  int m = gid >> 4, j = gid & 15;
  const float* xr = x + (size_t)m * H_;
  float s = 0.f;
  for (int k = 0; k < H_; k += 4) {
    float4 xv = *(const float4*)&xr[k];
    s = fmaf(xv.x, Wgk1[(k + 0) * LR_ + j], s);
    s = fmaf(xv.y, Wgk1[(k + 1) * LR_ + j], s);
    s = fmaf(xv.z, Wgk1[(k + 2) * LR_ + j], s);
    s = fmaf(xv.w, Wgk1[(k + 3) * LR_ + j], s);
  }
  xg1[gid] = s;
}

__global__ __launch_bounds__(256) void gk_kernel(const float* __restrict__ xg1,
                                                 const float* __restrict__ Wgk2,
                                                 const float* __restrict__ bgk2,
                                                 float* __restrict__ gk) {
  int gid = blockIdx.x * 256 + threadIdx.x;
  int m = gid >> 9, n = gid & 511;
  const float* xr = xg1 + m * LR_;
  float s = bgk2[n];
#pragma unroll
  for (int r = 0; r < LR_; ++r) s = fmaf(xr[r], Wgk2[r * DK_ + n], s);
  float ls = fminf(s, 0.f) - log1pf(__expf(-fabsf(s)));
  gk[gid] = ls * (1.0f / 16.0f);
}

// ---------------------------------------------------------------------------
// prep: gcum prefix; bf16 outputs Q~,Kinv [2048][512]; KdecT bf16 [unit][128][64];
// D = exp(Gtot). grid 128 units.
// ---------------------------------------------------------------------------
__global__ __launch_bounds__(256) void prep2(const float* __restrict__ gk,
                                             const u16* __restrict__ Pb,
                                             u16* __restrict__ qtb,
                                             u16* __restrict__ kinvb,
                                             u16* __restrict__ kdecTb,
                                             float* __restrict__ D) {
  __shared__ float gc[64][129];
  __shared__ u16 kbuf[64][129];
  int unit = blockIdx.x;
  int c = unit & 15, bh = unit >> 4;
  int b = bh >> 2, h = bh & 3;
  int tid = threadIdx.x;
  int brow = b * T_ + c * CHUNK;
  size_t gbase = (size_t)brow * 512 + h * 128;
  if (tid < 128) {
    float g = 0.f;
    for (int i = 0; i < 64; ++i) {
      g += gk[gbase + (size_t)i * 512 + tid];
      gc[i][tid] = g;
    }
    D[unit * 128 + tid] = __expf(g);
  }
  __syncthreads();
  const float scale = 0.08838834764831845f;
  const u16* Pq = Pb + (size_t)brow * 3072 + h * 128;
  const u16* Pk = Pq + 512;
#pragma unroll 4
  for (int e = 0; e < 32; ++e) {
    int idx = e * 256 + tid;
    int i = idx >> 7, j = idx & 127;
    float gv = gc[i][j];
    u16 ku = Pk[(size_t)i * 3072 + j];
    kbuf[i][j] = ku;
    float qv = bf2f(Pq[(size_t)i * 3072 + j]);
    float kv = bf2f(ku);
    qtb[gbase + (size_t)i * 512 + j]   = f2bf(qv * __expf(gv) * scale);
    kinvb[gbase + (size_t)i * 512 + j] = f2bf(kv * __expf(-gv));
  }
  __syncthreads();
  u16* kd = kdecTb + (size_t)unit * 8192;
#pragma unroll 4
  for (int e = 0; e < 32; ++e) {
    int idx = e * 256 + tid;
    int j = idx >> 6, i = idx & 63;
    float kv = bf2f(kbuf[i][j]);
    float gv = gc[i][j];
    float G  = gc[63][j];
    kd[(size_t)j * 64 + i] = f2bf(kv * __expf(G - gv));
  }
}

// ---------------------------------------------------------------------------
// Vt[bh][vc][t] = bf16 V from P v-slice. grid (32 t-tiles, 8 vc-tiles, 8 bh).
// ---------------------------------------------------------------------------
__global__ __launch_bounds__(256) void vtrans(const u16* __restrict__ Pb,
                                              u16* __restrict__ Vtb) {
  __shared__ u16 tile[32][33];
  int tt = blockIdx.x, vt = blockIdx.y, bh = blockIdx.z;
  int b = bh >> 2, h = bh & 3;
  int tx = threadIdx.x & 31, ty = threadIdx.x >> 5;
  const u16* src = Pb + (size_t)(b * T_ + tt * 32) * 3072 + 1024 + h * 256 + vt * 32;
#pragma unroll
  for (int i = 0; i < 32; i += 8)
    tile[ty + i][tx] = src[(size_t)(ty + i) * 3072 + tx];
  __syncthreads();
  u16* dst = Vtb + (size_t)bh * 262144 + (size_t)(vt * 32) * 1024 + tt * 32;
#pragma unroll
  for (int i = 0; i < 32; i += 8)
    dst[(size_t)(ty + i) * 1024 + tx] = tile[tx][ty + i];
}

// ---------------------------------------------------------------------------
// Ut[c][bh][vc][kd] = (KdecT @ V)^T = Vt_rows x KdecT_rows (MFMA).
// grid (vh 0..1, c 0..14, bh 0..7).
// ---------------------------------------------------------------------------
__global__ __launch_bounds__(256) void state_mfma(const u16* __restrict__ Vtb,
                                                  const u16* __restrict__ kdecTb,
                                                  float* __restrict__ Ut) {
  __shared__ u16 Asm[8192];   // 128 vc-rows x 64 t
  __shared__ u16 Bsm[8192];   // 128 j-rows  x 64 t
  int vh = blockIdx.x, c = blockIdx.y, bh = blockIdx.z;
  int unit = bh * 16 + c;
  int tid = threadIdx.x, w = tid >> 6, l = tid & 63;
  int lrow = l & 15, g4 = l >> 4;

  int r = tid >> 3;
  int csrc = ((tid & 7) ^ (r & 7)) << 3;
  const u16* Av = Vtb + (size_t)bh * 262144 + (size_t)(vh * 128 + r) * 1024 + c * 64 + csrc;
  const u16* Bk = kdecTb + (size_t)unit * 8192 + (size_t)r * 64 + csrc;
#pragma unroll
  for (int i = 0; i < 4; ++i) {
    gll16(Av + (size_t)i * 32 * 1024, (char*)Asm + i * 4096 + (w << 10));
    gll16(Bk + (size_t)i * 32 * 64,   (char*)Bsm + i * 4096 + (w << 10));
  }
  __syncthreads();
  f32x4 acc[2][8] = {};
#pragma unroll
  for (int ks = 0; ks < 2; ++ks) {
    bf16x8 a[2], bb[8];
#pragma unroll
    for (int mi = 0; mi < 2; ++mi) {
      int row = w * 32 + mi * 16 + lrow;
      a[mi] = *(const bf16x8*)(Asm + row * 64 + ((((ks << 2) + g4) ^ (row & 7)) << 3));
    }
#pragma unroll
    for (int nj = 0; nj < 8; ++nj) {
      int row = nj * 16 + lrow;
      bb[nj] = *(const bf16x8*)(Bsm + row * 64 + ((((ks << 2) + g4) ^ (row & 7)) << 3));
    }
#pragma unroll
    for (int mi = 0; mi < 2; ++mi)
#pragma unroll
      for (int nj = 0; nj < 8; ++nj)
        acc[mi][nj] = __builtin_amdgcn_mfma_f32_16x16x32_bf16(a[mi], bb[nj], acc[mi][nj], 0, 0, 0);
  }
  float* Ub = Ut + (size_t)(c * 8 + bh) * 32768;
#pragma unroll
  for (int mi = 0; mi < 2; ++mi)
#pragma unroll
    for (int nj = 0; nj < 8; ++nj)
#pragma unroll
      for (int j = 0; j < 4; ++j) {
        int vc = vh * 128 + w * 32 + mi * 16 + (g4 << 2) + j;
        int kd = nj * 16 + lrow;
        Ub[(size_t)vc * 128 + kd] = acc[mi][nj][j];
      }
}

// ---------------------------------------------------------------------------
// combine: S^T running recurrence, emits bf16 StT slots 0..15 (slot 0 = 0).
// ---------------------------------------------------------------------------
__global__ __launch_bounds__(256) void combine2(const float* __restrict__ D,
                                                const float* __restrict__ Ut,
                                                u16* __restrict__ StT) {
  int cell = blockIdx.x * 256 + threadIdx.x;   // 262144
  int bh = cell >> 15, r = cell & 32767, kd = r & 127;
  StT[(size_t)bh * 32768 + r] = 0;
  float S = 0.f;
  for (int c = 0; c < 15; ++c) {
    S = fmaf(D[(bh * 16 + c) * 128 + kd], S, Ut[((size_t)c * 8 + bh) * 32768 + r]);
    StT[((size_t)(c + 1) * 8 + bh) * 32768 + r] = f2bf(S);
  }
}

// ---------------------------------------------------------------------------
// Fused per-unit: A = mask(Q~ Kinv^T); O = A V + Q~ S; RMSNorm*gw*swish(g) -> bf16.
// grid 128 units, 4 waves (wave w owns 64-col v-slice).
// ---------------------------------------------------------------------------
__global__ __launch_bounds__(256) void fused_out(const u16* __restrict__ qtb,
                                                 const u16* __restrict__ kinvb,
                                                 const u16* __restrict__ Vtb,
                                                 const u16* __restrict__ StTb,
                                                 const u16* __restrict__ Pb,
                                                 const float* __restrict__ gw,
                                                 u16* __restrict__ onb) {
  __shared__ u16 Qs[8192];    // 64 rows x 128 kd (swizzled)
  __shared__ u16 As[4096];    // 64 rows x 64 t (swizzled)
  __shared__ float rsum[64][4];
  int unit = blockIdx.x;
  int c = unit & 15, bh = unit >> 4;
  int b = bh >> 2, h = bh & 3;
  int tid = threadIdx.x, w = tid >> 6, l = tid & 63;
  int lrow = l & 15, g4 = l >> 4, lx = l & 7;
  int brow = b * T_ + c * CHUNK;

  // stage Q~ tile [64][128]
  {
    int r0 = tid >> 4;
    int csrc = ((tid & 15) ^ (r0 & 7)) << 3;
    const u16* src = qtb + (size_t)(brow + r0) * 512 + h * 128 + csrc;
#pragma unroll
    for (int i = 0; i < 4; ++i)
      gll16(src + (size_t)i * 16 * 512, (char*)Qs + i * 4096 + (w << 10));
  }
  // phase-1 B-frags: Kinv direct global
  const u16* Kbase = kinvb + (size_t)brow * 512 + h * 128;
  bf16x8 bk[4][4];
#pragma unroll
  for (int nj = 0; nj < 4; ++nj)
#pragma unroll
    for (int ks = 0; ks < 4; ++ks)
      bk[nj][ks] = *(const bf16x8*)(Kbase + (size_t)(nj * 16 + lrow) * 512 + ks * 32 + (g4 << 3));
  __syncthreads();

  // phase 1: wave w computes A rows [w*16, w*16+16)
  f32x4 accA[4] = {};
  {
    int arow = w * 16 + lrow;
#pragma unroll
    for (int ks = 0; ks < 4; ++ks) {
      bf16x8 aq = *(const bf16x8*)(Qs + arow * 128 + ((((ks << 2) + g4) ^ lx) << 3));
#pragma unroll
      for (int nj = 0; nj < 4; ++nj)
        accA[nj] = __builtin_amdgcn_mfma_f32_16x16x32_bf16(aq, bk[nj][ks], accA[nj], 0, 0, 0);
    }
  }
#pragma unroll
  for (int nj = 0; nj < 4; ++nj)
#pragma unroll
    for (int j = 0; j < 4; ++j) {
      int rg = w * 16 + (g4 << 2) + j;
      int col = nj * 16 + lrow;
      float vv = (col <= rg) ? accA[nj][j] : 0.f;
      int chunk = ((nj << 1) + (lrow >> 3)) ^ (rg & 7);
      As[rg * 64 + (chunk << 3) + (lrow & 7)] = f2bf(vv);
    }
  __syncthreads();

  // phases 2+3
  f32x4 acc[4][4] = {};
  const u16* Vbase = Vtb + (size_t)bh * 262144 + (size_t)(w * 64) * 1024 + c * 64;
  const u16* Sbase = StTb + (((size_t)(c * 8 + bh)) * 256 + w * 64) * 128;
#pragma unroll
  for (int ks2 = 0; ks2 < 2; ++ks2) {
    bf16x8 bv[4];
#pragma unroll
    for (int nj = 0; nj < 4; ++nj)
      bv[nj] = *(const bf16x8*)(Vbase + (size_t)(nj * 16 + lrow) * 1024 + ks2 * 32 + (g4 << 3));
#pragma unroll
    for (int mi = 0; mi < 4; ++mi) {
      int row = mi * 16 + lrow;
      int chunk = ((ks2 << 2) + g4) ^ (row & 7);
      bf16x8 aa = *(const bf16x8*)(As + row * 64 + (chunk << 3));
#pragma unroll
      for (int nj = 0; nj < 4; ++nj)
        acc[mi][nj] = __builtin_amdgcn_mfma_f32_16x16x32_bf16(aa, bv[nj], acc[mi][nj], 0, 0, 0);
    }
  }
#pragma unroll
  for (int ks = 0; ks < 4; ++ks) {
    bf16x8 bs[4];
#pragma unroll
    for (int nj = 0; nj < 4; ++nj)
      bs[nj] = *(const bf16x8*)(Sbase + (size_t)(nj * 16 + lrow) * 128 + ks * 32 + (g4 << 3));
#pragma unroll
    for (int mi = 0; mi < 4; ++mi) {
      int row = mi * 16 + lrow;
      bf16x8 aq = *(const bf16x8*)(Qs + row * 128 + ((((ks << 2) + g4) ^ lx) << 3));
#pragma unroll
      for (int nj = 0; nj < 4; ++nj)
        acc[mi][nj] = __builtin_amdgcn_mfma_f32_16x16x32_bf16(aq, bs[nj], acc[mi][nj], 0, 0, 0);
    }
  }

  // epilogue: RMS over 256 cols (cross-wave), then gate
#pragma unroll
  for (int mi = 0; mi < 4; ++mi)
#pragma unroll
    for (int j = 0; j < 4; ++j) {
      float s = 0.f;
#pragma unroll
      for (int nj = 0; nj < 4; ++nj) { float o = acc[mi][nj][j]; s = fmaf(o, o, s); }
      s += __shfl_xor(s, 1);
      s += __shfl_xor(s, 2);
      s += __shfl_xor(s, 4);
      s += __shfl_xor(s, 8);
      if (lrow == 0) rsum[mi * 16 + (g4 << 2) + j][w] = s;
    }
  __syncthreads();
  const u16* Gbase = Pb + (size_t)brow * 3072 + 2048 + h * 256;
#pragma unroll
  for (int mi = 0; mi < 4; ++mi)
#pragma unroll
    for (int j = 0; j < 4; ++j) {
      int row = mi * 16 + (g4 << 2) + j;
      float4 rs = *(float4*)&rsum[row][0];
      float rn = rsqrtf((rs.x + rs.y + rs.z + rs.w) * (1.f / 256.f) + 1e-5f);
#pragma unroll
      for (int nj = 0; nj < 4; ++nj) {
        int vc = w * 64 + nj * 16 + lrow;
        float o = acc[mi][nj][j] * rn * gw[vc];
        float gval = bf2f(Gbase[(size_t)row * 3072 + vc]);
        float sw = gval / (1.f + __expf(-gval));
        onb[(size_t)(brow + row) * 1024 + h * 256 + vc] = f2bf(o * sw);
      }
    }
}

// ---------------------------------------------------------------------------
extern "C" void kernel_launch(void* const* d_in, const int* in_sizes, int n_in,
                              void* d_out, int out_size, void* d_ws, size_t ws_size,
                              hipStream_t stream) {
  const float* x    = (const float*)d_in[0];
  const float* Wq   = (const float*)d_in[1];
  const float* Wk   = (const float*)d_in[2];
  const float* Wv   = (const float*)d_in[3];
  const float* Wgk1 = (const float*)d_in[4];
  const float* Wgk2 = (const float*)d_in[5];
  const float* bgk2 = (const float*)d_in[6];
  const float* Wg   = (const float*)d_in[7];
  const float* Wo   = (const float*)d_in[8];
  const float* gw   = (const float*)d_in[9];
  float* out = (float*)d_out;

  float* F = (float*)d_ws;
  // float-offset layout (total 13,418,496 floats = 53.7 MB)
  u16*   Pb     = (u16*)F;                      // 2048x3072 bf16
  u16*   Wotb   = (u16*)(F + 3145728);          // 1024x1024 bf16
  u16*   xbb    = (u16*)(F + 3670016);          // x bf16; later qtb/kinvb
  float* xg1    = F + 4718592;
  float* gkbuf  = F + 4751360;
  u16*   WallTb = (u16*)(F + 5799936);          // 3072x1024 bf16; later kdecT+Vt
  float* D      = F + 7372800;
  float* Ut     = F + 7389184;                  // 15x8x32768 f32; later onb
  u16*   StT    = (u16*)(F + 11321344);         // 16x8x32768 bf16

  u16* qtb    = xbb;                    // after proj GEMM, xb is dead
  u16* kinvb  = xbb + 1048576;
  u16* kdecTb = WallTb;                 // after proj GEMM, WallT is dead
  u16* Vtb    = WallTb + 1048576;
  u16* onb    = (u16*)Ut;               // after combine, Ut is dead

  dim3 blk(256);
  conv_x<<<2048, blk, 0, stream>>>(x, xbb);
  transpose_bf16<<<dim3(16, 32), blk, 0, stream>>>(Wq, WallTb, H_, DK_);
  transpose_bf16<<<dim3(16, 32), blk, 0, stream>>>(Wk, WallTb + 512 * 1024, H_, DK_);
  transpose_bf16<<<dim3(32, 32), blk, 0, stream>>>(Wv, WallTb + 1024 * 1024, H_, DV_);
  transpose_bf16<<<dim3(32, 32), blk, 0, stream>>>(Wg, WallTb + 2048 * 1024, H_, DV_);
  transpose_bf16<<<dim3(32, 32), blk, 0, stream>>>(Wo, Wotb, DV_, H_);

  gemm_bf16_t<true><<<dim3(48, 32), blk, 0, stream>>>(xbb, WallTb, Pb, 2048, 3072, H_);

  lr1_kernel<<<128, blk, 0, stream>>>(x, Wgk1, xg1);
  gk_kernel<<<4096, blk, 0, stream>>>(xg1, Wgk2, bgk2, gkbuf);

  prep2<<<128, blk, 0, stream>>>(gkbuf, Pb, qtb, kinvb, kdecTb, D);
  vtrans<<<dim3(32, 8, 8), blk, 0, stream>>>(Pb, Vtb);
  state_mfma<<<dim3(2, 15, 8), blk, 0, stream>>>(Vtb, kdecTb, Ut);
  combine2<<<1024, blk, 0, stream>>>(D, Ut, StT);
  fused_out<<<128, blk, 0, stream>>>(qtb, kinvb, Vtb, StT, Pb, gw, onb);

  gemm_bf16_t<false><<<dim3(16, 32), blk, 0, stream>>>(onb, Wotb, out, 2048, H_, DV_);
}

// Round 5
// 127.384 us; speedup vs baseline: 7.9655x; 1.0179x over previous
//
#include <hip/hip_runtime.h>
#include <math.h>

#define T_  1024
#define H_  1024
#define DK_ 512
#define DV_ 1024
#define LR_ 16
#define CHUNK 64

using f32x4  = __attribute__((ext_vector_type(4))) float;
using bf16x8 = __attribute__((ext_vector_type(8))) short;
using u16x4  = __attribute__((ext_vector_type(4))) unsigned short;
typedef unsigned short u16;

__device__ __forceinline__ u16 f2bf(float f) {
  union { float f; unsigned int u; } v; v.f = f;
  unsigned int r = v.u + 0x7FFF + ((v.u >> 16) & 1);
  return (u16)(r >> 16);
}
__device__ __forceinline__ float bf2f(u16 u) {
  union { unsigned int i; float f; } v; v.i = ((unsigned int)u) << 16;
  return v.f;
}
__device__ __forceinline__ void gll16(const void* g, void* l) {
  __builtin_amdgcn_global_load_lds((const __attribute__((address_space(1))) void*)g,
                                   (__attribute__((address_space(3))) void*)l, 16, 0, 0);
}

// ---------------------------------------------------------------------------
// 128x128-tile bf16 MFMA GEMM: C[M,N] = A[M,K] @ Bt[N,K]. BK=64, 4 waves,
// each wave 64x64 (4x4 16x16x32 frags). Chunk-XOR swizzle both sides.
// ---------------------------------------------------------------------------
template <bool OBF>
__global__ __launch_bounds__(256) void gemm128(const u16* __restrict__ A,
                                               const u16* __restrict__ Bt,
                                               void* __restrict__ Cv,
                                               int M, int N, int K) {
  __shared__ u16 Asm[8192];   // 128 x 64
  __shared__ u16 Bsm[8192];
  int tid = threadIdx.x, w = tid >> 6, l = tid & 63;
  int bm = blockIdx.y << 7, bn = blockIdx.x << 7;

  int srow = (w << 3) + (l >> 3);            // 0..31
  int schunk = ((l & 7) ^ (l >> 3)) << 3;    // source elem offset in k
  const u16* pA = A  + (size_t)(bm + srow) * K + schunk;
  const u16* pB = Bt + (size_t)(bn + srow) * K + schunk;
  char* AsmB = (char*)Asm;
  char* BsmB = (char*)Bsm;
  int ldsw = w << 10;

  int wr = w >> 1, wc = w & 1;
  int lrow = l & 15, g4 = l >> 4, lx = l & 7;

  f32x4 acc[4][4] = {};
  for (int k0 = 0; k0 < K; k0 += 64) {
#pragma unroll
    for (int i = 0; i < 4; ++i) {
      gll16(pA + (size_t)(i * 32) * K + k0, AsmB + i * 4096 + ldsw);
      gll16(pB + (size_t)(i * 32) * K + k0, BsmB + i * 4096 + ldsw);
    }
    __syncthreads();
    bf16x8 a[4][2], b[4][2];
#pragma unroll
    for (int mi = 0; mi < 4; ++mi)
#pragma unroll
      for (int ks = 0; ks < 2; ++ks) {
        int ar = wr * 64 + mi * 16 + lrow;
        int br = wc * 64 + mi * 16 + lrow;
        a[mi][ks] = *(const bf16x8*)(Asm + ar * 64 + ((((ks << 2) + g4) ^ lx) << 3));
        b[mi][ks] = *(const bf16x8*)(Bsm + br * 64 + ((((ks << 2) + g4) ^ lx) << 3));
      }
#pragma unroll
    for (int ks = 0; ks < 2; ++ks)
#pragma unroll
      for (int mi = 0; mi < 4; ++mi)
#pragma unroll
        for (int ni = 0; ni < 4; ++ni)
          acc[mi][ni] = __builtin_amdgcn_mfma_f32_16x16x32_bf16(
              a[mi][ks], b[ni][ks], acc[mi][ni], 0, 0, 0);
    __syncthreads();
  }
#pragma unroll
  for (int mi = 0; mi < 4; ++mi)
#pragma unroll
    for (int ni = 0; ni < 4; ++ni) {
      int row0 = bm + wr * 64 + mi * 16 + (g4 << 2);
      int col  = bn + wc * 64 + ni * 16 + lrow;
#pragma unroll
      for (int j = 0; j < 4; ++j) {
        if (OBF) ((u16*)Cv)[(size_t)(row0 + j) * N + col] = f2bf(acc[mi][ni][j]);
        else     ((float*)Cv)[(size_t)(row0 + j) * N + col] = acc[mi][ni][j];
      }
    }
}

// ---------------------------------------------------------------------------
// 64x64-tile bf16 GEMM (kept for the skinny xg1 projection, N=64).
// ---------------------------------------------------------------------------
template <bool OBF>
__global__ __launch_bounds__(256) void gemm64(const u16* __restrict__ A,
                                              const u16* __restrict__ Bt,
                                              void* __restrict__ Cv,
                                              int M, int N, int K) {
  __shared__ short Asm[4096];
  __shared__ short Bsm[4096];
  int tid = threadIdx.x;
  int w = tid >> 6, l = tid & 63;
  int bm = blockIdx.y << 6, bn = blockIdx.x << 6;

  int srow = (w << 3) + (l >> 3);
  int schunk = ((l & 7) ^ (l >> 3)) << 3;
  const u16* pA0 = A  + (size_t)(bm + srow) * K + schunk;
  const u16* pA1 = A  + (size_t)(bm + 32 + srow) * K + schunk;
  const u16* pB0 = Bt + (size_t)(bn + srow) * K + schunk;
  const u16* pB1 = Bt + (size_t)(bn + 32 + srow) * K + schunk;
  char* AsmB = (char*)Asm;
  char* BsmB = (char*)Bsm;
  int ldsw = w << 10;

  int ro = (w >> 1) << 5, co = (w & 1) << 5;
  int lrow = l & 15, g4 = l >> 4, lx = l & 7;

  f32x4 acc[2][2] = {};
  for (int k0 = 0; k0 < K; k0 += 64) {
    gll16(pA0 + k0, AsmB + ldsw);
    gll16(pA1 + k0, AsmB + 4096 + ldsw);
    gll16(pB0 + k0, BsmB + ldsw);
    gll16(pB1 + k0, BsmB + 4096 + ldsw);
    __syncthreads();
    bf16x8 a[2][2], b[2][2];
#pragma unroll
    for (int mi = 0; mi < 2; ++mi)
#pragma unroll
      for (int ks = 0; ks < 2; ++ks) {
        a[mi][ks] = *(const bf16x8*)(Asm + (ro + mi * 16 + lrow) * 64 + ((((ks << 2) + g4) ^ lx) << 3));
        b[mi][ks] = *(const bf16x8*)(Bsm + (co + mi * 16 + lrow) * 64 + ((((ks << 2) + g4) ^ lx) << 3));
      }
#pragma unroll
    for (int mi = 0; mi < 2; ++mi)
#pragma unroll
      for (int ni = 0; ni < 2; ++ni)
#pragma unroll
        for (int ks = 0; ks < 2; ++ks)
          acc[mi][ni] = __builtin_amdgcn_mfma_f32_16x16x32_bf16(
              a[mi][ks], b[ni][ks], acc[mi][ni], 0, 0, 0);
    __syncthreads();
  }
#pragma unroll
  for (int mi = 0; mi < 2; ++mi)
#pragma unroll
    for (int ni = 0; ni < 2; ++ni) {
      int row0 = bm + ro + mi * 16 + (g4 << 2);
      int col  = bn + co + ni * 16 + lrow;
#pragma unroll
      for (int j = 0; j < 4; ++j) {
        if (OBF) ((u16*)Cv)[(size_t)(row0 + j) * N + col] = f2bf(acc[mi][ni][j]);
        else     ((float*)Cv)[(size_t)(row0 + j) * N + col] = acc[mi][ni][j];
      }
    }
}

// ---------------------------------------------------------------------------
// Fused misc prep: z=0..4 weight transposes (f32 -> bf16 [N][K]), z=5 x->bf16,
// z=6 Wgk1 [1024][16] -> zero-padded bf16 [64][1024].
// ---------------------------------------------------------------------------
__global__ __launch_bounds__(256) void prep_misc(const float* __restrict__ x,
                                                 const float* __restrict__ Wq,
                                                 const float* __restrict__ Wk,
                                                 const float* __restrict__ Wv,
                                                 const float* __restrict__ Wg,
                                                 const float* __restrict__ Wo,
                                                 const float* __restrict__ Wgk1,
                                                 u16* __restrict__ xbb,
                                                 u16* __restrict__ WallTb,
                                                 u16* __restrict__ Wotb,
                                                 u16* __restrict__ WgkTb) {
  int z = blockIdx.z;
  int tid = threadIdx.x;
  if (z == 5) {
    size_t i0 = ((size_t)(blockIdx.y * 32 + blockIdx.x)) * 2048 + tid * 4;
    float4 v0 = *(const float4*)&x[i0];
    float4 v1 = *(const float4*)&x[i0 + 1024];
    u16x4 o0 = {f2bf(v0.x), f2bf(v0.y), f2bf(v0.z), f2bf(v0.w)};
    u16x4 o1 = {f2bf(v1.x), f2bf(v1.y), f2bf(v1.z), f2bf(v1.w)};
    *(u16x4*)&xbb[i0] = o0;
    *(u16x4*)&xbb[i0 + 1024] = o1;
    return;
  }
  if (z == 6) {
    if (blockIdx.x != 0) return;
    int col = blockIdx.y * 32 + (tid & 31);
#pragma unroll
    for (int i = 0; i < 8; ++i) {
      int oc = (tid >> 5) + i * 8;   // 0..63
      float v = (oc < LR_) ? Wgk1[(size_t)col * LR_ + oc] : 0.f;
      WgkTb[(size_t)oc * 1024 + col] = f2bf(v);
    }
    return;
  }
  const float* in; u16* outp; int R, C;
  if (z == 0)      { in = Wq; outp = WallTb;               R = 1024; C = 512; }
  else if (z == 1) { in = Wk; outp = WallTb + 512 * 1024;  R = 1024; C = 512; }
  else if (z == 2) { in = Wv; outp = WallTb + 1024 * 1024; R = 1024; C = 1024; }
  else if (z == 3) { in = Wg; outp = WallTb + 2048 * 1024; R = 1024; C = 1024; }
  else             { in = Wo; outp = Wotb;                 R = 1024; C = 1024; }
  int bx = blockIdx.x << 5, by = blockIdx.y << 5;
  if (bx >= C) return;
  __shared__ float tile[32][33];
  int tx = tid & 31, ty = tid >> 5;
#pragma unroll
  for (int i = 0; i < 32; i += 8)
    tile[ty + i][tx] = in[(size_t)(by + ty + i) * C + bx + tx];
  __syncthreads();
#pragma unroll
  for (int i = 0; i < 32; i += 8)
    outp[(size_t)(bx + ty + i) * R + by + tx] = f2bf(tile[tx][ty + i]);
}

// ---------------------------------------------------------------------------
// prep2: inline low-rank gate (xg1 @ Wgk2 + b -> logsigmoid/16 -> prefix),
// emits bf16 Q~, Kinv, KdecT and fp32 D. grid 128 units.
// ---------------------------------------------------------------------------
__global__ __launch_bounds__(256) void prep2(const float* __restrict__ xg1,
                                             const float* __restrict__ Wgk2,
                                             const float* __restrict__ bgk2,
                                             const u16* __restrict__ Pb,
                                             u16* __restrict__ qtb,
                                             u16* __restrict__ kinvb,
                                             u16* __restrict__ kdecTb,
                                             float* __restrict__ D) {
  __shared__ float gc[64][129];
  __shared__ u16 kbuf[64][129];
  __shared__ float xs[64][17];
  int unit = blockIdx.x;
  int c = unit & 15, bh = unit >> 4;
  int b = bh >> 2, h = bh & 3;
  int tid = threadIdx.x;
  int brow = b * T_ + c * CHUNK;
  size_t gbase = (size_t)brow * 512 + h * 128;

#pragma unroll
  for (int e = 0; e < 4; ++e) {
    int idx = e * 256 + tid;
    xs[idx >> 4][idx & 15] = xg1[(size_t)(brow + (idx >> 4)) * 64 + (idx & 15)];
  }
  __syncthreads();
  if (tid < 128) {
    int n = h * 128 + tid;
    float w2[LR_];
#pragma unroll
    for (int r = 0; r < LR_; ++r) w2[r] = Wgk2[r * DK_ + n];
    float bb = bgk2[n];
    float g = 0.f;
    for (int i = 0; i < 64; ++i) {
      float sv = bb;
#pragma unroll
      for (int r = 0; r < LR_; ++r) sv = fmaf(xs[i][r], w2[r], sv);
      float ls = fminf(sv, 0.f) - log1pf(__expf(-fabsf(sv)));
      g += ls * (1.0f / 16.0f);
      gc[i][tid] = g;
    }
    D[unit * 128 + tid] = __expf(g);
  }
  __syncthreads();

  const float scale = 0.08838834764831845f;
  const u16* Pq = Pb + (size_t)brow * 3072 + h * 128;
  const u16* Pk = Pq + 512;
#pragma unroll 4
  for (int e = 0; e < 32; ++e) {
    int idx = e * 256 + tid;
    int i = idx >> 7, j = idx & 127;
    float gv = gc[i][j];
    u16 ku = Pk[(size_t)i * 3072 + j];
    kbuf[i][j] = ku;
    float qv = bf2f(Pq[(size_t)i * 3072 + j]);
    float kv = bf2f(ku);
    qtb[gbase + (size_t)i * 512 + j]   = f2bf(qv * __expf(gv) * scale);
    kinvb[gbase + (size_t)i * 512 + j] = f2bf(kv * __expf(-gv));
  }
  __syncthreads();
  u16* kd = kdecTb + (size_t)unit * 8192;
#pragma unroll 4
  for (int e = 0; e < 32; ++e) {
    int idx = e * 256 + tid;
    int j = idx >> 6, i = idx & 63;
    float kv = bf2f(kbuf[i][j]);
    float gv = gc[i][j];
    float G  = gc[63][j];
    kd[(size_t)j * 64 + i] = f2bf(kv * __expf(G - gv));
  }
}

// ---------------------------------------------------------------------------
// Vt[bh][vc][t] = bf16 V from P v-slice. grid (32, 8, 8).
// ---------------------------------------------------------------------------
__global__ __launch_bounds__(256) void vtrans(const u16* __restrict__ Pb,
                                              u16* __restrict__ Vtb) {
  __shared__ u16 tile[32][33];
  int tt = blockIdx.x, vt = blockIdx.y, bh = blockIdx.z;
  int b = bh >> 2, h = bh & 3;
  int tx = threadIdx.x & 31, ty = threadIdx.x >> 5;
  const u16* src = Pb + (size_t)(b * T_ + tt * 32) * 3072 + 1024 + h * 256 + vt * 32;
#pragma unroll
  for (int i = 0; i < 32; i += 8)
    tile[ty + i][tx] = src[(size_t)(ty + i) * 3072 + tx];
  __syncthreads();
  u16* dst = Vtb + (size_t)bh * 262144 + (size_t)(vt * 32) * 1024 + tt * 32;
#pragma unroll
  for (int i = 0; i < 32; i += 8)
    dst[(size_t)(ty + i) * 1024 + tx] = tile[tx][ty + i];
}

// ---------------------------------------------------------------------------
// Ut[c][bh][vc][kd] = (KdecT @ V)^T via MFMA. grid (2, 15, 8).
// ---------------------------------------------------------------------------
__global__ __launch_bounds__(256) void state_mfma(const u16* __restrict__ Vtb,
                                                  const u16* __restrict__ kdecTb,
                                                  float* __restrict__ Ut) {
  __shared__ u16 Asm[8192];
  __shared__ u16 Bsm[8192];
  int vh = blockIdx.x, c = blockIdx.y, bh = blockIdx.z;
  int unit = bh * 16 + c;
  int tid = threadIdx.x, w = tid >> 6, l = tid & 63;
  int lrow = l & 15, g4 = l >> 4;

  int r = tid >> 3;
  int csrc = ((tid & 7) ^ (r & 7)) << 3;
  const u16* Av = Vtb + (size_t)bh * 262144 + (size_t)(vh * 128 + r) * 1024 + c * 64 + csrc;
  const u16* Bk = kdecTb + (size_t)unit * 8192 + (size_t)r * 64 + csrc;
#pragma unroll
  for (int i = 0; i < 4; ++i) {
    gll16(Av + (size_t)i * 32 * 1024, (char*)Asm + i * 4096 + (w << 10));
    gll16(Bk + (size_t)i * 32 * 64,   (char*)Bsm + i * 4096 + (w << 10));
  }
  __syncthreads();
  f32x4 acc[2][8] = {};
#pragma unroll
  for (int ks = 0; ks < 2; ++ks) {
    bf16x8 a[2], bb[8];
#pragma unroll
    for (int mi = 0; mi < 2; ++mi) {
      int row = w * 32 + mi * 16 + lrow;
      a[mi] = *(const bf16x8*)(Asm + row * 64 + ((((ks << 2) + g4) ^ (row & 7)) << 3));
    }
#pragma unroll
    for (int nj = 0; nj < 8; ++nj) {
      int row = nj * 16 + lrow;
      bb[nj] = *(const bf16x8*)(Bsm + row * 64 + ((((ks << 2) + g4) ^ (row & 7)) << 3));
    }
#pragma unroll
    for (int mi = 0; mi < 2; ++mi)
#pragma unroll
      for (int nj = 0; nj < 8; ++nj)
        acc[mi][nj] = __builtin_amdgcn_mfma_f32_16x16x32_bf16(a[mi], bb[nj], acc[mi][nj], 0, 0, 0);
  }
  float* Ub = Ut + (size_t)(c * 8 + bh) * 32768;
#pragma unroll
  for (int mi = 0; mi < 2; ++mi)
#pragma unroll
    for (int nj = 0; nj < 8; ++nj)
#pragma unroll
      for (int j = 0; j < 4; ++j) {
        int vc = vh * 128 + w * 32 + mi * 16 + (g4 << 2) + j;
        int kd = nj * 16 + lrow;
        Ub[(size_t)vc * 128 + kd] = acc[mi][nj][j];
      }
}

// ---------------------------------------------------------------------------
// combine: S^T recurrence, emits bf16 StT slots 0..15 (slot 0 = 0).
// ---------------------------------------------------------------------------
__global__ __launch_bounds__(256) void combine2(const float* __restrict__ D,
                                                const float* __restrict__ Ut,
                                                u16* __restrict__ StT) {
  int cell = blockIdx.x * 256 + threadIdx.x;
  int bh = cell >> 15, r = cell & 32767, kd = r & 127;
  StT[(size_t)bh * 32768 + r] = 0;
  float S = 0.f;
  for (int c = 0; c < 15; ++c) {
    S = fmaf(D[(bh * 16 + c) * 128 + kd], S, Ut[((size_t)c * 8 + bh) * 32768 + r]);
    StT[((size_t)(c + 1) * 8 + bh) * 32768 + r] = f2bf(S);
  }
}

// ---------------------------------------------------------------------------
// Fused per-half-unit: A = mask(Q~ Kinv^T); O = A V + Q~ S; RMSNorm*gw*swish.
// grid 256 = (unit 0..127) x (row-half s). 32 rows x 256 v-cols per block.
// ---------------------------------------------------------------------------
__global__ __launch_bounds__(256) void fused_out(const u16* __restrict__ qtb,
                                                 const u16* __restrict__ kinvb,
                                                 const u16* __restrict__ Vtb,
                                                 const u16* __restrict__ StTb,
                                                 const u16* __restrict__ Pb,
                                                 const float* __restrict__ gw,
                                                 u16* __restrict__ onb) {
  __shared__ u16 Qs[4096];    // 32 x 128 (swizzled)
  __shared__ u16 As[2048];    // 32 x 64  (swizzled)
  __shared__ float rsum[32][4];
  int bx = blockIdx.x;
  int unit = bx >> 1, s = bx & 1;
  int c = unit & 15, bh = unit >> 4;
  int b = bh >> 2, h = bh & 3;
  int tid = threadIdx.x, w = tid >> 6, l = tid & 63;
  int lrow = l & 15, g4 = l >> 4, lx = l & 7;
  int crow = b * T_ + c * CHUNK;
  int brow = crow + s * 32;

  // stage Q [32][128]: 2 issues
  {
    int r0 = tid >> 4;
    int csrc = ((tid & 15) ^ (r0 & 7)) << 3;
    const u16* src = qtb + (size_t)(brow + r0) * 512 + h * 128 + csrc;
    gll16(src, (char*)Qs + (w << 10));
    gll16(src + 16 * 512, (char*)Qs + 4096 + (w << 10));
  }
  // phase-1 B-frags: Kinv rows = all 64 keys of the chunk
  const u16* Kbase = kinvb + (size_t)crow * 512 + h * 128;
  int wc1 = w & 1, fr = w >> 1;
  bf16x8 bk[2][4];
#pragma unroll
  for (int nj = 0; nj < 2; ++nj)
#pragma unroll
    for (int ks = 0; ks < 4; ++ks)
      bk[nj][ks] = *(const bf16x8*)(Kbase + (size_t)(wc1 * 32 + nj * 16 + lrow) * 512 + ks * 32 + (g4 << 3));
  __syncthreads();

  // phase 1: wave w computes A rows [fr*16,+16) x cols [wc1*32,+32)
  f32x4 accA[2] = {};
#pragma unroll
  for (int ks = 0; ks < 4; ++ks) {
    int arow = fr * 16 + lrow;
    bf16x8 aq = *(const bf16x8*)(Qs + arow * 128 + ((((ks << 2) + g4) ^ lx) << 3));
#pragma unroll
    for (int nj = 0; nj < 2; ++nj)
      accA[nj] = __builtin_amdgcn_mfma_f32_16x16x32_bf16(aq, bk[nj][ks], accA[nj], 0, 0, 0);
  }
#pragma unroll
  for (int nj = 0; nj < 2; ++nj)
#pragma unroll
    for (int j = 0; j < 4; ++j) {
      int rg = fr * 16 + (g4 << 2) + j;          // local row 0..31
      int col = wc1 * 32 + nj * 16 + lrow;       // key position 0..63
      float vv = (col <= s * 32 + rg) ? accA[nj][j] : 0.f;
      int chunk = (col >> 3) ^ (rg & 7);
      As[rg * 64 + (chunk << 3) + (lrow & 7)] = f2bf(vv);
    }
  __syncthreads();

  // phases 2+3: wave w owns v-cols [w*64,+64), rows 0..32
  f32x4 acc[2][4] = {};
  const u16* Vbase = Vtb + (size_t)bh * 262144 + (size_t)(w * 64) * 1024 + c * 64;
  const u16* Sbase = StTb + (((size_t)(c * 8 + bh)) * 256 + w * 64) * 128;
#pragma unroll
  for (int ks2 = 0; ks2 < 2; ++ks2) {
    bf16x8 bv[4];
#pragma unroll
    for (int nj = 0; nj < 4; ++nj)
      bv[nj] = *(const bf16x8*)(Vbase + (size_t)(nj * 16 + lrow) * 1024 + ks2 * 32 + (g4 << 3));
#pragma unroll
    for (int mi = 0; mi < 2; ++mi) {
      int row = mi * 16 + lrow;
      bf16x8 aa = *(const bf16x8*)(As + row * 64 + ((((ks2 << 2) + g4) ^ lx) << 3));
#pragma unroll
      for (int nj = 0; nj < 4; ++nj)
        acc[mi][nj] = __builtin_amdgcn_mfma_f32_16x16x32_bf16(aa, bv[nj], acc[mi][nj], 0, 0, 0);
    }
  }
#pragma unroll
  for (int ks = 0; ks < 4; ++ks) {
    bf16x8 bs[4];
#pragma unroll
    for (int nj = 0; nj < 4; ++nj)
      bs[nj] = *(const bf16x8*)(Sbase + (size_t)(nj * 16 + lrow) * 128 + ks * 32 + (g4 << 3));
#pragma unroll
    for (int mi = 0; mi < 2; ++mi) {
      int row = mi * 16 + lrow;
      bf16x8 aq = *(const bf16x8*)(Qs + row * 128 + ((((ks << 2) + g4) ^ lx) << 3));
#pragma unroll
      for (int nj = 0; nj < 4; ++nj)
        acc[mi][nj] = __builtin_amdgcn_mfma_f32_16x16x32_bf16(aq, bs[nj], acc[mi][nj], 0, 0, 0);
    }
  }

  // epilogue: RMS over 256 cols (cross-wave) + swish gate
#pragma unroll
  for (int mi = 0; mi < 2; ++mi)
#pragma unroll
    for (int j = 0; j < 4; ++j) {
      float ss = 0.f;
#pragma unroll
      for (int nj = 0; nj < 4; ++nj) { float o = acc[mi][nj][j]; ss = fmaf(o, o, ss); }
      ss += __shfl_xor(ss, 1);
      ss += __shfl_xor(ss, 2);
      ss += __shfl_xor(ss, 4);
      ss += __shfl_xor(ss, 8);
      if (lrow == 0) rsum[mi * 16 + (g4 << 2) + j][w] = ss;
    }
  __syncthreads();
  const u16* Gbase = Pb + (size_t)brow * 3072 + 2048 + h * 256;
#pragma unroll
  for (int mi = 0; mi < 2; ++mi)
#pragma unroll
    for (int j = 0; j < 4; ++j) {
      int row = mi * 16 + (g4 << 2) + j;
      float4 rs = *(float4*)&rsum[row][0];
      float rn = rsqrtf((rs.x + rs.y + rs.z + rs.w) * (1.f / 256.f) + 1e-5f);
#pragma unroll
      for (int nj = 0; nj < 4; ++nj) {
        int vc = w * 64 + nj * 16 + lrow;
        float o = acc[mi][nj][j] * rn * gw[vc];
        float gval = bf2f(Gbase[(size_t)row * 3072 + vc]);
        float sw = gval / (1.f + __expf(-gval));
        onb[(size_t)(brow + row) * 1024 + h * 256 + vc] = f2bf(o * sw);
      }
    }
}

// ---------------------------------------------------------------------------
extern "C" void kernel_launch(void* const* d_in, const int* in_sizes, int n_in,
                              void* d_out, int out_size, void* d_ws, size_t ws_size,
                              hipStream_t stream) {
  const float* x    = (const float*)d_in[0];
  const float* Wq   = (const float*)d_in[1];
  const float* Wk   = (const float*)d_in[2];
  const float* Wv   = (const float*)d_in[3];
  const float* Wgk1 = (const float*)d_in[4];
  const float* Wgk2 = (const float*)d_in[5];
  const float* bgk2 = (const float*)d_in[6];
  const float* Wg   = (const float*)d_in[7];
  const float* Wo   = (const float*)d_in[8];
  const float* gw   = (const float*)d_in[9];
  float* out = (float*)d_out;

  float* F = (float*)d_ws;
  u16*   Pb     = (u16*)F;                       // 2048x3072 bf16
  u16*   WallTb = (u16*)(F + 3145728);           // 3072x1024 bf16 -> kdecT + Vt
  u16*   Wotb   = (u16*)(F + 4718592);           // 1024x1024 bf16
  u16*   xbb    = (u16*)(F + 5242880);           // x bf16 -> qtb + kinvb
  u16*   WgkTb  = (u16*)(F + 6291456);           // 64x1024 bf16
  float* xg1    = F + 6324224;                   // 2048x64 f32
  float* D      = F + 6455296;                   // 16384
  float* Ut     = F + 6471680;                   // 15x8x32768 f32 -> onb
  u16*   StT    = (u16*)(F + 10403840);          // 16x8x32768 bf16 (end 12.5M floats)

  u16* qtb    = xbb;
  u16* kinvb  = xbb + 1048576;
  u16* kdecTb = WallTb;
  u16* Vtb    = WallTb + 1048576;
  u16* onb    = (u16*)Ut;

  dim3 blk(256);
  prep_misc<<<dim3(32, 32, 7), blk, 0, stream>>>(x, Wq, Wk, Wv, Wg, Wo, Wgk1,
                                                 xbb, WallTb, Wotb, WgkTb);
  gemm128<true><<<dim3(24, 16), blk, 0, stream>>>(xbb, WallTb, Pb, 2048, 3072, H_);
  gemm64<false><<<dim3(1, 32), blk, 0, stream>>>(xbb, WgkTb, xg1, 2048, 64, H_);
  prep2<<<128, blk, 0, stream>>>(xg1, Wgk2, bgk2, Pb, qtb, kinvb, kdecTb, D);
  vtrans<<<dim3(32, 8, 8), blk, 0, stream>>>(Pb, Vtb);
  state_mfma<<<dim3(2, 15, 8), blk, 0, stream>>>(Vtb, kdecTb, Ut);
  combine2<<<1024, blk, 0, stream>>>(D, Ut, StT);
  fused_out<<<256, blk, 0, stream>>>(qtb, kinvb, Vtb, StT, Pb, gw, onb);
  gemm128<false><<<dim3(8, 16), blk, 0, stream>>>(onb, Wotb, out, 2048, H_, DV_);
}

// Round 6
// 108.950 us; speedup vs baseline: 9.3132x; 1.1692x over previous
//
#include <hip/hip_runtime.h>
#include <math.h>

#define T_  1024
#define H_  1024
#define DK_ 512
#define DV_ 1024
#define LR_ 16
#define CHUNK 64
#define PN  3200   // fused projection width: q(512)|k(512)|v(1024)|g(1024)|xg1pad(128)

using f32x4  = __attribute__((ext_vector_type(4))) float;
using bf16x8 = __attribute__((ext_vector_type(8))) short;
using u16x4  = __attribute__((ext_vector_type(4))) unsigned short;
typedef unsigned short u16;

__device__ __forceinline__ u16 f2bf(float f) {
  union { float f; unsigned int u; } v; v.f = f;
  unsigned int r = v.u + 0x7FFF + ((v.u >> 16) & 1);
  return (u16)(r >> 16);
}
__device__ __forceinline__ float bf2f(u16 u) {
  union { unsigned int i; float f; } v; v.i = ((unsigned int)u) << 16;
  return v.f;
}
__device__ __forceinline__ void gll16(const void* g, void* l) {
  __builtin_amdgcn_global_load_lds((const __attribute__((address_space(1))) void*)g,
                                   (__attribute__((address_space(3))) void*)l, 16, 0, 0);
}

// ---------------------------------------------------------------------------
// 128x128-tile bf16 MFMA GEMM: C[M,N] = A[M,K] @ Bt[N,K]. BK=64, 4 waves.
// VT: blocks in the V column range also emit the transposed tile to Vtb.
// ---------------------------------------------------------------------------
template <bool OBF, bool VT>
__global__ __launch_bounds__(256) void gemm128(const u16* __restrict__ A,
                                               const u16* __restrict__ Bt,
                                               void* __restrict__ Cv,
                                               u16* __restrict__ Vtb,
                                               int M, int N, int K) {
  __shared__ u16 Asm[8192];   // 128 x 64
  __shared__ u16 Bsm[8192];
  int tid = threadIdx.x, w = tid >> 6, l = tid & 63;
  int bm = blockIdx.y << 7, bn = blockIdx.x << 7;

  int srow = (w << 3) + (l >> 3);
  int schunk = ((l & 7) ^ (l >> 3)) << 3;
  const u16* pA = A  + (size_t)(bm + srow) * K + schunk;
  const u16* pB = Bt + (size_t)(bn + srow) * K + schunk;
  char* AsmB = (char*)Asm;
  char* BsmB = (char*)Bsm;
  int ldsw = w << 10;

  int wr = w >> 1, wc = w & 1;
  int lrow = l & 15, g4 = l >> 4, lx = l & 7;

  f32x4 acc[4][4] = {};
  for (int k0 = 0; k0 < K; k0 += 64) {
#pragma unroll
    for (int i = 0; i < 4; ++i) {
      gll16(pA + (size_t)(i * 32) * K + k0, AsmB + i * 4096 + ldsw);
      gll16(pB + (size_t)(i * 32) * K + k0, BsmB + i * 4096 + ldsw);
    }
    __syncthreads();
    bf16x8 a[4][2], b[4][2];
#pragma unroll
    for (int mi = 0; mi < 4; ++mi)
#pragma unroll
      for (int ks = 0; ks < 2; ++ks) {
        int ar = wr * 64 + mi * 16 + lrow;
        int br = wc * 64 + mi * 16 + lrow;
        a[mi][ks] = *(const bf16x8*)(Asm + ar * 64 + ((((ks << 2) + g4) ^ lx) << 3));
        b[mi][ks] = *(const bf16x8*)(Bsm + br * 64 + ((((ks << 2) + g4) ^ lx) << 3));
      }
#pragma unroll
    for (int ks = 0; ks < 2; ++ks)
#pragma unroll
      for (int mi = 0; mi < 4; ++mi)
#pragma unroll
        for (int ni = 0; ni < 4; ++ni)
          acc[mi][ni] = __builtin_amdgcn_mfma_f32_16x16x32_bf16(
              a[mi][ks], b[ni][ks], acc[mi][ni], 0, 0, 0);
    __syncthreads();
  }
#pragma unroll
  for (int mi = 0; mi < 4; ++mi)
#pragma unroll
    for (int ni = 0; ni < 4; ++ni) {
      int row0 = bm + wr * 64 + mi * 16 + (g4 << 2);
      int col  = bn + wc * 64 + ni * 16 + lrow;
#pragma unroll
      for (int j = 0; j < 4; ++j) {
        if (OBF) ((u16*)Cv)[(size_t)(row0 + j) * N + col] = f2bf(acc[mi][ni][j]);
        else     ((float*)Cv)[(size_t)(row0 + j) * N + col] = acc[mi][ni][j];
      }
    }
  if (VT && bn >= 1024 && bn < 2048) {   // also emit V^T for this tile
    int h = (bn - 1024) >> 8;
    int bb_ = bm >> 10;
    u16* vt = Vtb + (size_t)(bb_ * 4 + h) * 262144;
    int tbase = bm & 1023;
#pragma unroll
    for (int mi = 0; mi < 4; ++mi)
#pragma unroll
      for (int ni = 0; ni < 4; ++ni) {
        int vcl = ((bn - 1024) & 255) + wc * 64 + ni * 16 + lrow;
        int t0 = tbase + wr * 64 + mi * 16 + (g4 << 2);
        u16x4 o = {f2bf(acc[mi][ni][0]), f2bf(acc[mi][ni][1]),
                   f2bf(acc[mi][ni][2]), f2bf(acc[mi][ni][3])};
        *(u16x4*)&vt[(size_t)vcl * 1024 + t0] = o;
      }
  }
}

// ---------------------------------------------------------------------------
// Fused misc prep: z=0..3 weight transposes into fused WallTb, z=4 Wo->Wotb,
// z=5 x->bf16, z=6 Wgk1^T zero-padded into WallTb rows 3072..3199.
// ---------------------------------------------------------------------------
__global__ __launch_bounds__(256) void prep_misc(const float* __restrict__ x,
                                                 const float* __restrict__ Wq,
                                                 const float* __restrict__ Wk,
                                                 const float* __restrict__ Wv,
                                                 const float* __restrict__ Wg,
                                                 const float* __restrict__ Wo,
                                                 const float* __restrict__ Wgk1,
                                                 u16* __restrict__ xbb,
                                                 u16* __restrict__ WallTb,
                                                 u16* __restrict__ Wotb) {
  int z = blockIdx.z;
  int tid = threadIdx.x;
  if (z == 5) {
    size_t i0 = ((size_t)(blockIdx.y * 32 + blockIdx.x)) * 2048 + tid * 4;
    float4 v0 = *(const float4*)&x[i0];
    float4 v1 = *(const float4*)&x[i0 + 1024];
    u16x4 o0 = {f2bf(v0.x), f2bf(v0.y), f2bf(v0.z), f2bf(v0.w)};
    u16x4 o1 = {f2bf(v1.x), f2bf(v1.y), f2bf(v1.z), f2bf(v1.w)};
    *(u16x4*)&xbb[i0] = o0;
    *(u16x4*)&xbb[i0 + 1024] = o1;
    return;
  }
  if (z == 6) {
    if (blockIdx.x != 0) return;
    int col = blockIdx.y * 32 + (tid & 31);
#pragma unroll
    for (int i = 0; i < 16; ++i) {
      int rr = (tid >> 5) + i * 8;   // 0..127
      float v = (rr < LR_) ? Wgk1[(size_t)col * LR_ + rr] : 0.f;
      WallTb[(size_t)(3072 + rr) * 1024 + col] = f2bf(v);
    }
    return;
  }
  const float* in; u16* outp; int C;
  if (z == 0)      { in = Wq; outp = WallTb;               C = 512; }
  else if (z == 1) { in = Wk; outp = WallTb + 512 * 1024;  C = 512; }
  else if (z == 2) { in = Wv; outp = WallTb + 1024 * 1024; C = 1024; }
  else if (z == 3) { in = Wg; outp = WallTb + 2048 * 1024; C = 1024; }
  else             { in = Wo; outp = Wotb;                 C = 1024; }
  int bx = blockIdx.x << 5, by = blockIdx.y << 5;
  if (bx >= C) return;
  __shared__ float tile[32][33];
  int tx = tid & 31, ty = tid >> 5;
#pragma unroll
  for (int i = 0; i < 32; i += 8)
    tile[ty + i][tx] = in[(size_t)(by + ty + i) * C + bx + tx];
  __syncthreads();
#pragma unroll
  for (int i = 0; i < 32; i += 8)
    outp[(size_t)(bx + ty + i) * 1024 + by + tx] = f2bf(tile[tx][ty + i]);
}

// ---------------------------------------------------------------------------
// prep2: gate (xg1@Wgk2+b -> logsigmoid/16 -> prefix), bf16 Q~/Kinv/KdecT, D.
// grid 128 units. xg1 read as bf16 from Pb cols 3072..3087.
// ---------------------------------------------------------------------------
__global__ __launch_bounds__(256) void prep2(const float* __restrict__ Wgk2,
                                             const float* __restrict__ bgk2,
                                             const u16* __restrict__ Pb,
                                             u16* __restrict__ qtb,
                                             u16* __restrict__ kinvb,
                                             u16* __restrict__ kdecTb,
                                             float* __restrict__ D) {
  __shared__ float gc[64][129];
  __shared__ u16 kbuf[64][129];
  __shared__ float xs[64][17];
  int unit = blockIdx.x;
  int c = unit & 15, bh = unit >> 4;
  int b = bh >> 2, h = bh & 3;
  int tid = threadIdx.x;
  int brow = b * T_ + c * CHUNK;
  size_t gbase = (size_t)brow * 512 + h * 128;

#pragma unroll
  for (int e = 0; e < 4; ++e) {
    int idx = e * 256 + tid;
    int i = idx >> 4, r = idx & 15;
    xs[i][r] = bf2f(Pb[(size_t)(brow + i) * PN + 3072 + r]);
  }
  __syncthreads();
  // pass 1: log-sigmoid gates, 256 threads (fixed j per thread)
  {
    int j = tid & 127, i0 = tid >> 7;
    int n = h * 128 + j;
    float w2[LR_];
#pragma unroll
    for (int r = 0; r < LR_; ++r) w2[r] = Wgk2[r * DK_ + n];
    float bb = bgk2[n];
#pragma unroll 4
    for (int e = 0; e < 32; ++e) {
      int i = e * 2 + i0;
      float sv = bb;
#pragma unroll
      for (int r = 0; r < LR_; ++r) sv = fmaf(xs[i][r], w2[r], sv);
      float ls = fminf(sv, 0.f) - log1pf(__expf(-fabsf(sv)));
      gc[i][j] = ls * (1.0f / 16.0f);
    }
  }
  __syncthreads();
  if (tid < 128) {
    float g = 0.f;
    for (int i = 0; i < 64; ++i) { g += gc[i][tid]; gc[i][tid] = g; }
    D[unit * 128 + tid] = __expf(g);
  }
  __syncthreads();

  const float scale = 0.08838834764831845f;
  const u16* Pq = Pb + (size_t)brow * PN + h * 128;
  const u16* Pk = Pq + 512;
#pragma unroll 4
  for (int e = 0; e < 32; ++e) {
    int idx = e * 256 + tid;
    int i = idx >> 7, j = idx & 127;
    float gv = gc[i][j];
    u16 ku = Pk[(size_t)i * PN + j];
    kbuf[i][j] = ku;
    float qv = bf2f(Pq[(size_t)i * PN + j]);
    float kv = bf2f(ku);
    qtb[gbase + (size_t)i * 512 + j]   = f2bf(qv * __expf(gv) * scale);
    kinvb[gbase + (size_t)i * 512 + j] = f2bf(kv * __expf(-gv));
  }
  __syncthreads();
  u16* kd = kdecTb + (size_t)unit * 8192;
#pragma unroll 4
  for (int e = 0; e < 32; ++e) {
    int idx = e * 256 + tid;
    int j = idx >> 6, i = idx & 63;
    float kv = bf2f(kbuf[i][j]);
    float gv = gc[i][j];
    float G  = gc[63][j];
    kd[(size_t)j * 64 + i] = f2bf(kv * __expf(G - gv));
  }
}

// ---------------------------------------------------------------------------
// state_combine: per (kh, vs, bh) block, V^T slice resident in LDS; for each
// chunk c: U = KdecT@V (MFMA, KdecT double-buffered), S = D*S + U in regs,
// StT[c+1] written bf16. Slot 0 zeroed. grid (2, 16, 8).
// ---------------------------------------------------------------------------
__global__ __launch_bounds__(256) void state_combine(const u16* __restrict__ Vtb,
                                                     const u16* __restrict__ kdecTb,
                                                     const float* __restrict__ D,
                                                     u16* __restrict__ StT) {
  __shared__ u16 VtS[16384];    // 16 v-rows x 1024 t (chunk-swizzled)
  __shared__ u16 Kdb[2][4096];  // 64 k-rows x 64 t, double-buffered
  int kh = blockIdx.x, vs = blockIdx.y, bh = blockIdx.z;
  int tid = threadIdx.x, w = tid >> 6, l = tid & 63;
  int lrow = l & 15, g4 = l >> 4;
  int unit0 = bh * 16;

  // stage V^T slice once
  {
    const u16* base = Vtb + (size_t)bh * 262144 + (size_t)(vs * 16) * 1024;
#pragma unroll
    for (int i = 0; i < 8; ++i) {
      int slin = i * 256 + w * 64 + l;
      int row = slin >> 7, chd = slin & 127;
      gll16(base + (size_t)row * 1024 + ((chd ^ (row & 7)) << 3),
            (char*)VtS + i * 4096 + (w << 10));
    }
  }
  // zero slot 0 (this block's cells); wave w owns k-rows [w*16, +16)
  int vc = vs * 16 + lrow;
  int kd0 = kh * 64 + w * 16 + (g4 << 2);
  {
    u16x4 z = {0, 0, 0, 0};
    *(u16x4*)&StT[(size_t)bh * 32768 + (size_t)vc * 128 + kd0] = z;
  }
  // prologue: stage KdecT chunk 0
  {
    const u16* kb = kdecTb + (size_t)unit0 * 8192 + (size_t)(kh * 64) * 64;
#pragma unroll
    for (int i = 0; i < 2; ++i) {
      int slin = i * 256 + w * 64 + l;
      int row = slin >> 3, chd = slin & 7;
      gll16(kb + (size_t)row * 64 + ((chd ^ (row & 7)) << 3),
            (char*)Kdb[0] + i * 4096 + (w << 10));
    }
  }
  f32x4 S = {};
  int cur = 0;
  for (int c = 0; c < 15; ++c) {
    __syncthreads();                 // Kdb[cur] (and VtS) ready
    if (c < 14) {
      const u16* kb = kdecTb + (size_t)(unit0 + c + 1) * 8192 + (size_t)(kh * 64) * 64;
#pragma unroll
      for (int i = 0; i < 2; ++i) {
        int slin = i * 256 + w * 64 + l;
        int row = slin >> 3, chd = slin & 7;
        gll16(kb + (size_t)row * 64 + ((chd ^ (row & 7)) << 3),
              (char*)Kdb[cur ^ 1] + i * 4096 + (w << 10));
      }
    }
    const u16* Kc = Kdb[cur];
    f32x4 acc = {};
#pragma unroll
    for (int ks = 0; ks < 2; ++ks) {
      int cidx = c * 8 + ks * 4 + g4;
      bf16x8 bv = *(const bf16x8*)(VtS + lrow * 1024 + ((cidx ^ (lrow & 7)) << 3));
      int row = w * 16 + lrow;
      bf16x8 av = *(const bf16x8*)(Kc + row * 64 + ((((ks << 2) + g4) ^ (row & 7)) << 3));
      acc = __builtin_amdgcn_mfma_f32_16x16x32_bf16(av, bv, acc, 0, 0, 0);
    }
    float4 dv = *(const float4*)&D[(size_t)(unit0 + c) * 128 + kd0];
    S[0] = fmaf(dv.x, S[0], acc[0]);
    S[1] = fmaf(dv.y, S[1], acc[1]);
    S[2] = fmaf(dv.z, S[2], acc[2]);
    S[3] = fmaf(dv.w, S[3], acc[3]);
    u16x4 o = {f2bf(S[0]), f2bf(S[1]), f2bf(S[2]), f2bf(S[3])};
    *(u16x4*)&StT[((size_t)(c + 1) * 8 + bh) * 32768 + (size_t)vc * 128 + kd0] = o;
    cur ^= 1;
  }
}

// ---------------------------------------------------------------------------
// Fused per-half-unit: A = mask(Q~ Kinv^T); O = A V + Q~ S; RMSNorm*gw*swish.
// grid 256 = (unit) x (row-half s). 32 rows x 256 v-cols per block.
// ---------------------------------------------------------------------------
__global__ __launch_bounds__(256) void fused_out(const u16* __restrict__ qtb,
                                                 const u16* __restrict__ kinvb,
                                                 const u16* __restrict__ Vtb,
                                                 const u16* __restrict__ StTb,
                                                 const u16* __restrict__ Pb,
                                                 const float* __restrict__ gw,
                                                 u16* __restrict__ onb) {
  __shared__ u16 Qs[4096];
  __shared__ u16 As[2048];
  __shared__ float rsum[32][4];
  int bx = blockIdx.x;
  int unit = bx >> 1, s = bx & 1;
  int c = unit & 15, bh = unit >> 4;
  int b = bh >> 2, h = bh & 3;
  int tid = threadIdx.x, w = tid >> 6, l = tid & 63;
  int lrow = l & 15, g4 = l >> 4, lx = l & 7;
  int crow = b * T_ + c * CHUNK;
  int brow = crow + s * 32;

  {
    int r0 = tid >> 4;
    int csrc = ((tid & 15) ^ (r0 & 7)) << 3;
    const u16* src = qtb + (size_t)(brow + r0) * 512 + h * 128 + csrc;
    gll16(src, (char*)Qs + (w << 10));
    gll16(src + 16 * 512, (char*)Qs + 4096 + (w << 10));
  }
  const u16* Kbase = kinvb + (size_t)crow * 512 + h * 128;
  int wc1 = w & 1, fr = w >> 1;
  bf16x8 bk[2][4];
#pragma unroll
  for (int nj = 0; nj < 2; ++nj)
#pragma unroll
    for (int ks = 0; ks < 4; ++ks)
      bk[nj][ks] = *(const bf16x8*)(Kbase + (size_t)(wc1 * 32 + nj * 16 + lrow) * 512 + ks * 32 + (g4 << 3));
  __syncthreads();

  f32x4 accA[2] = {};
#pragma unroll
  for (int ks = 0; ks < 4; ++ks) {
    int arow = fr * 16 + lrow;
    bf16x8 aq = *(const bf16x8*)(Qs + arow * 128 + ((((ks << 2) + g4) ^ lx) << 3));
#pragma unroll
    for (int nj = 0; nj < 2; ++nj)
      accA[nj] = __builtin_amdgcn_mfma_f32_16x16x32_bf16(aq, bk[nj][ks], accA[nj], 0, 0, 0);
  }
#pragma unroll
  for (int nj = 0; nj < 2; ++nj)
#pragma unroll
    for (int j = 0; j < 4; ++j) {
      int rg = fr * 16 + (g4 << 2) + j;
      int col = wc1 * 32 + nj * 16 + lrow;
      float vv = (col <= s * 32 + rg) ? accA[nj][j] : 0.f;
      int chunk = (col >> 3) ^ (rg & 7);
      As[rg * 64 + (chunk << 3) + (lrow & 7)] = f2bf(vv);
    }
  __syncthreads();

  f32x4 acc[2][4] = {};
  const u16* Vbase = Vtb + (size_t)bh * 262144 + (size_t)(w * 64) * 1024 + c * 64;
  const u16* Sbase = StTb + (((size_t)(c * 8 + bh)) * 256 + w * 64) * 128;
#pragma unroll
  for (int ks2 = 0; ks2 < 2; ++ks2) {
    bf16x8 bv[4];
#pragma unroll
    for (int nj = 0; nj < 4; ++nj)
      bv[nj] = *(const bf16x8*)(Vbase + (size_t)(nj * 16 + lrow) * 1024 + ks2 * 32 + (g4 << 3));
#pragma unroll
    for (int mi = 0; mi < 2; ++mi) {
      int row = mi * 16 + lrow;
      bf16x8 aa = *(const bf16x8*)(As + row * 64 + ((((ks2 << 2) + g4) ^ lx) << 3));
#pragma unroll
      for (int nj = 0; nj < 4; ++nj)
        acc[mi][nj] = __builtin_amdgcn_mfma_f32_16x16x32_bf16(aa, bv[nj], acc[mi][nj], 0, 0, 0);
    }
  }
#pragma unroll
  for (int ks = 0; ks < 4; ++ks) {
    bf16x8 bs[4];
#pragma unroll
    for (int nj = 0; nj < 4; ++nj)
      bs[nj] = *(const bf16x8*)(Sbase + (size_t)(nj * 16 + lrow) * 128 + ks * 32 + (g4 << 3));
#pragma unroll
    for (int mi = 0; mi < 2; ++mi) {
      int row = mi * 16 + lrow;
      bf16x8 aq = *(const bf16x8*)(Qs + row * 128 + ((((ks << 2) + g4) ^ lx) << 3));
#pragma unroll
      for (int nj = 0; nj < 4; ++nj)
        acc[mi][nj] = __builtin_amdgcn_mfma_f32_16x16x32_bf16(aq, bs[nj], acc[mi][nj], 0, 0, 0);
    }
  }

#pragma unroll
  for (int mi = 0; mi < 2; ++mi)
#pragma unroll
    for (int j = 0; j < 4; ++j) {
      float ss = 0.f;
#pragma unroll
      for (int nj = 0; nj < 4; ++nj) { float o = acc[mi][nj][j]; ss = fmaf(o, o, ss); }
      ss += __shfl_xor(ss, 1);
      ss += __shfl_xor(ss, 2);
      ss += __shfl_xor(ss, 4);
      ss += __shfl_xor(ss, 8);
      if (lrow == 0) rsum[mi * 16 + (g4 << 2) + j][w] = ss;
    }
  __syncthreads();
  const u16* Gbase = Pb + (size_t)brow * PN + 2048 + h * 256;
#pragma unroll
  for (int mi = 0; mi < 2; ++mi)
#pragma unroll
    for (int j = 0; j < 4; ++j) {
      int row = mi * 16 + (g4 << 2) + j;
      float4 rs = *(float4*)&rsum[row][0];
      float rn = rsqrtf((rs.x + rs.y + rs.z + rs.w) * (1.f / 256.f) + 1e-5f);
#pragma unroll
      for (int nj = 0; nj < 4; ++nj) {
        int vc = w * 64 + nj * 16 + lrow;
        float o = acc[mi][nj][j] * rn * gw[vc];
        float gval = bf2f(Gbase[(size_t)row * PN + vc]);
        float sw = gval / (1.f + __expf(-gval));
        onb[(size_t)(brow + row) * 1024 + h * 256 + vc] = f2bf(o * sw);
      }
    }
}

// ---------------------------------------------------------------------------
extern "C" void kernel_launch(void* const* d_in, const int* in_sizes, int n_in,
                              void* d_out, int out_size, void* d_ws, size_t ws_size,
                              hipStream_t stream) {
  const float* x    = (const float*)d_in[0];
  const float* Wq   = (const float*)d_in[1];
  const float* Wk   = (const float*)d_in[2];
  const float* Wv   = (const float*)d_in[3];
  const float* Wgk1 = (const float*)d_in[4];
  const float* Wgk2 = (const float*)d_in[5];
  const float* bgk2 = (const float*)d_in[6];
  const float* Wg   = (const float*)d_in[7];
  const float* Wo   = (const float*)d_in[8];
  const float* gw   = (const float*)d_in[9];
  float* out = (float*)d_out;

  float* F = (float*)d_ws;
  u16*   Pb     = (u16*)F;                       // [2048][3200] bf16
  u16*   WallTb = (u16*)(F + 3276800);           // [3200][1024] bf16 -> kdecT+onb
  u16*   Wotb   = (u16*)(F + 4915200);           // [1024][1024] bf16
  u16*   xbb    = (u16*)(F + 5439488);           // x bf16 -> qtb+kinvb
  u16*   Vtb    = (u16*)(F + 6488064);           // [8][256][1024] bf16
  float* D      = F + 7536640;                   // [128][128] f32
  u16*   StT    = (u16*)(F + 7553024);           // [16][8][32768] bf16 (end 9.65M f)

  u16* qtb    = xbb;                             // aliases (xbb dead after proj)
  u16* kinvb  = xbb + 1048576;
  u16* kdecTb = WallTb;                          // WallTb dead after proj
  u16* onb    = WallTb + 1048576;

  dim3 blk(256);
  prep_misc<<<dim3(32, 32, 7), blk, 0, stream>>>(x, Wq, Wk, Wv, Wg, Wo, Wgk1,
                                                 xbb, WallTb, Wotb);
  gemm128<true, true><<<dim3(25, 16), blk, 0, stream>>>(xbb, WallTb, Pb, Vtb, 2048, PN, H_);
  prep2<<<128, blk, 0, stream>>>(Wgk2, bgk2, Pb, qtb, kinvb, kdecTb, D);
  state_combine<<<dim3(2, 16, 8), blk, 0, stream>>>(Vtb, kdecTb, D, StT);
  fused_out<<<256, blk, 0, stream>>>(qtb, kinvb, Vtb, StT, Pb, gw, onb);
  gemm128<false, false><<<dim3(8, 16), blk, 0, stream>>>(onb, Wotb, out, nullptr, 2048, H_, DV_);
}

// Round 7
// 95.662 us; speedup vs baseline: 10.6069x; 1.1389x over previous
//
#include <hip/hip_runtime.h>
#include <math.h>

#define T_  1024
#define H_  1024
#define DK_ 512
#define DV_ 1024
#define LR_ 16
#define CHUNK 64
#define PN  3200   // fused projection width: q(512)|k(512)|v(1024)|g(1024)|xg1pad(128)

using f32x4  = __attribute__((ext_vector_type(4))) float;
using f32x16 = __attribute__((ext_vector_type(16))) float;
using bf16x8 = __attribute__((ext_vector_type(8))) short;
using u16x4  = __attribute__((ext_vector_type(4))) unsigned short;
typedef unsigned short u16;

__device__ __forceinline__ u16 f2bf(float f) {
  union { float f; unsigned int u; } v; v.f = f;
  unsigned int r = v.u + 0x7FFF + ((v.u >> 16) & 1);
  return (u16)(r >> 16);
}
__device__ __forceinline__ float bf2f(u16 u) {
  union { unsigned int i; float f; } v; v.i = ((unsigned int)u) << 16;
  return v.f;
}
__device__ __forceinline__ void gll16(const void* g, void* l) {
  __builtin_amdgcn_global_load_lds((const __attribute__((address_space(1))) void*)g,
                                   (__attribute__((address_space(3))) void*)l, 16, 0, 0);
}

// ---------------------------------------------------------------------------
// 128x128-tile bf16 GEMM via mfma_f32_32x32x16: C[M,N] = A[M,K] @ Bt[N,K].
// BK=64, 4 waves, each wave 64x64 = 2x2 of 32x32 frags. XOR swizzle both sides.
// VT: blocks in the V column range also emit the transposed tile to Vtb.
// ---------------------------------------------------------------------------
template <bool OBF, bool VT>
__global__ __launch_bounds__(256) void gemm128(const u16* __restrict__ A,
                                               const u16* __restrict__ Bt,
                                               void* __restrict__ Cv,
                                               u16* __restrict__ Vtb,
                                               int M, int N, int K) {
  __shared__ u16 Asm[8192];   // 128 x 64
  __shared__ u16 Bsm[8192];
  int tid = threadIdx.x, w = tid >> 6, l = tid & 63;
  int bm = blockIdx.y << 7, bn = blockIdx.x << 7;

  int srow = (w << 3) + (l >> 3);
  int schunk = ((l & 7) ^ (l >> 3)) << 3;
  const u16* pA = A  + (size_t)(bm + srow) * K + schunk;
  const u16* pB = Bt + (size_t)(bn + srow) * K + schunk;
  char* AsmB = (char*)Asm;
  char* BsmB = (char*)Bsm;
  int ldsw = w << 10;

  int wr = w >> 1, wc = w & 1;
  int l31 = l & 31, hi = l >> 5;

  f32x16 acc[2][2] = {};
  for (int k0 = 0; k0 < K; k0 += 64) {
#pragma unroll
    for (int i = 0; i < 4; ++i) {
      gll16(pA + (size_t)(i * 32) * K + k0, AsmB + i * 4096 + ldsw);
      gll16(pB + (size_t)(i * 32) * K + k0, BsmB + i * 4096 + ldsw);
    }
    __syncthreads();
    bf16x8 a[2][4], b[2][4];
#pragma unroll
    for (int mi = 0; mi < 2; ++mi)
#pragma unroll
      for (int ks = 0; ks < 4; ++ks) {
        int ar = wr * 64 + mi * 32 + l31;
        int br = wc * 64 + mi * 32 + l31;
        a[mi][ks] = *(const bf16x8*)(Asm + ar * 64 + ((((ks << 1) + hi) ^ (ar & 7)) << 3));
        b[mi][ks] = *(const bf16x8*)(Bsm + br * 64 + ((((ks << 1) + hi) ^ (br & 7)) << 3));
      }
#pragma unroll
    for (int ks = 0; ks < 4; ++ks)
#pragma unroll
      for (int mi = 0; mi < 2; ++mi)
#pragma unroll
        for (int ni = 0; ni < 2; ++ni)
          acc[mi][ni] = __builtin_amdgcn_mfma_f32_32x32x16_bf16(
              a[mi][ks], b[ni][ks], acc[mi][ni], 0, 0, 0);
    __syncthreads();
  }
  // C/D: col = l&31, row = (reg&3) + 8*(reg>>2) + 4*(l>>5)
#pragma unroll
  for (int mi = 0; mi < 2; ++mi)
#pragma unroll
    for (int ni = 0; ni < 2; ++ni) {
      int colg = bn + wc * 64 + ni * 32 + l31;
#pragma unroll
      for (int q = 0; q < 4; ++q) {
        int row0 = bm + wr * 64 + mi * 32 + q * 8 + hi * 4;
#pragma unroll
        for (int j = 0; j < 4; ++j) {
          float vv = acc[mi][ni][q * 4 + j];
          if (OBF) ((u16*)Cv)[(size_t)(row0 + j) * N + colg] = f2bf(vv);
          else     ((float*)Cv)[(size_t)(row0 + j) * N + colg] = vv;
        }
      }
    }
  if (VT && bn >= 1024 && bn < 2048) {   // also emit V^T for this tile
    int h = (bn - 1024) >> 8;
    int bb_ = bm >> 10;
    u16* vt = Vtb + (size_t)(bb_ * 4 + h) * 262144;
    int tbase = bm & 1023;
#pragma unroll
    for (int mi = 0; mi < 2; ++mi)
#pragma unroll
      for (int ni = 0; ni < 2; ++ni) {
        int vcl = ((bn - 1024) & 255) + wc * 64 + ni * 32 + l31;
#pragma unroll
        for (int q = 0; q < 4; ++q) {
          int t0 = tbase + wr * 64 + mi * 32 + q * 8 + hi * 4;
          u16x4 o = {f2bf(acc[mi][ni][q * 4 + 0]), f2bf(acc[mi][ni][q * 4 + 1]),
                     f2bf(acc[mi][ni][q * 4 + 2]), f2bf(acc[mi][ni][q * 4 + 3])};
          *(u16x4*)&vt[(size_t)vcl * 1024 + t0] = o;
        }
      }
  }
}

// ---------------------------------------------------------------------------
// 128x64-tile bf16 GEMM (final Wo): grid (N/64, M/128) = 256 blocks.
// 4 waves, wave w owns rows [w*32,+32) x all 64 cols = 1x2 of 32x32 frags.
// ---------------------------------------------------------------------------
__global__ __launch_bounds__(256) void gemmWo(const u16* __restrict__ A,
                                              const u16* __restrict__ Bt,
                                              float* __restrict__ C,
                                              int M, int N, int K) {
  __shared__ u16 Asm[8192];   // 128 x 64
  __shared__ u16 Bsm[4096];   // 64 x 64
  int tid = threadIdx.x, w = tid >> 6, l = tid & 63;
  int bm = blockIdx.y << 7, bn = blockIdx.x << 6;

  int srow = (w << 3) + (l >> 3);
  int schunk = ((l & 7) ^ (l >> 3)) << 3;
  const u16* pA = A  + (size_t)(bm + srow) * K + schunk;
  const u16* pB = Bt + (size_t)(bn + srow) * K + schunk;
  char* AsmB = (char*)Asm;
  char* BsmB = (char*)Bsm;
  int ldsw = w << 10;
  int l31 = l & 31, hi = l >> 5;

  f32x16 acc[2] = {};
  for (int k0 = 0; k0 < K; k0 += 64) {
#pragma unroll
    for (int i = 0; i < 4; ++i)
      gll16(pA + (size_t)(i * 32) * K + k0, AsmB + i * 4096 + ldsw);
#pragma unroll
    for (int i = 0; i < 2; ++i)
      gll16(pB + (size_t)(i * 32) * K + k0, BsmB + i * 4096 + ldsw);
    __syncthreads();
    bf16x8 a[4], b[2][4];
#pragma unroll
    for (int ks = 0; ks < 4; ++ks) {
      int ar = w * 32 + l31;
      a[ks] = *(const bf16x8*)(Asm + ar * 64 + ((((ks << 1) + hi) ^ (ar & 7)) << 3));
#pragma unroll
      for (int ni = 0; ni < 2; ++ni) {
        int br = ni * 32 + l31;
        b[ni][ks] = *(const bf16x8*)(Bsm + br * 64 + ((((ks << 1) + hi) ^ (br & 7)) << 3));
      }
    }
#pragma unroll
    for (int ks = 0; ks < 4; ++ks)
#pragma unroll
      for (int ni = 0; ni < 2; ++ni)
        acc[ni] = __builtin_amdgcn_mfma_f32_32x32x16_bf16(a[ks], b[ni][ks], acc[ni], 0, 0, 0);
    __syncthreads();
  }
#pragma unroll
  for (int ni = 0; ni < 2; ++ni) {
    int colg = bn + ni * 32 + l31;
#pragma unroll
    for (int q = 0; q < 4; ++q) {
      int row0 = bm + w * 32 + q * 8 + hi * 4;
#pragma unroll
      for (int j = 0; j < 4; ++j)
        C[(size_t)(row0 + j) * N + colg] = acc[ni][q * 4 + j];
    }
  }
}

// ---------------------------------------------------------------------------
// Fused misc prep: z=0..3 weight transposes into fused WallTb, z=4 Wo->Wotb,
// z=5 x->bf16, z=6 Wgk1^T zero-padded into WallTb rows 3072..3199.
// ---------------------------------------------------------------------------
__global__ __launch_bounds__(256) void prep_misc(const float* __restrict__ x,
                                                 const float* __restrict__ Wq,
                                                 const float* __restrict__ Wk,
                                                 const float* __restrict__ Wv,
                                                 const float* __restrict__ Wg,
                                                 const float* __restrict__ Wo,
                                                 const float* __restrict__ Wgk1,
                                                 u16* __restrict__ xbb,
                                                 u16* __restrict__ WallTb,
                                                 u16* __restrict__ Wotb) {
  int z = blockIdx.z;
  int tid = threadIdx.x;
  if (z == 5) {
    size_t i0 = ((size_t)(blockIdx.y * 32 + blockIdx.x)) * 2048 + tid * 4;
    float4 v0 = *(const float4*)&x[i0];
    float4 v1 = *(const float4*)&x[i0 + 1024];
    u16x4 o0 = {f2bf(v0.x), f2bf(v0.y), f2bf(v0.z), f2bf(v0.w)};
    u16x4 o1 = {f2bf(v1.x), f2bf(v1.y), f2bf(v1.z), f2bf(v1.w)};
    *(u16x4*)&xbb[i0] = o0;
    *(u16x4*)&xbb[i0 + 1024] = o1;
    return;
  }
  if (z == 6) {
    if (blockIdx.x != 0) return;
    int col = blockIdx.y * 32 + (tid & 31);
#pragma unroll
    for (int i = 0; i < 16; ++i) {
      int rr = (tid >> 5) + i * 8;   // 0..127
      float v = (rr < LR_) ? Wgk1[(size_t)col * LR_ + rr] : 0.f;
      WallTb[(size_t)(3072 + rr) * 1024 + col] = f2bf(v);
    }
    return;
  }
  const float* in; u16* outp; int C;
  if (z == 0)      { in = Wq; outp = WallTb;               C = 512; }
  else if (z == 1) { in = Wk; outp = WallTb + 512 * 1024;  C = 512; }
  else if (z == 2) { in = Wv; outp = WallTb + 1024 * 1024; C = 1024; }
  else if (z == 3) { in = Wg; outp = WallTb + 2048 * 1024; C = 1024; }
  else             { in = Wo; outp = Wotb;                 C = 1024; }
  int bx = blockIdx.x << 5, by = blockIdx.y << 5;
  if (bx >= C) return;
  __shared__ float tile[32][33];
  int tx = tid & 31, ty = tid >> 5;
#pragma unroll
  for (int i = 0; i < 32; i += 8)
    tile[ty + i][tx] = in[(size_t)(by + ty + i) * C + bx + tx];
  __syncthreads();
#pragma unroll
  for (int i = 0; i < 32; i += 8)
    outp[(size_t)(bx + ty + i) * 1024 + by + tx] = f2bf(tile[tx][ty + i]);
}

// ---------------------------------------------------------------------------
// prep2: gate (xg1@Wgk2+b -> logsigmoid/16 -> prefix), bf16 Q~/Kinv/KdecT, D.
// grid 256 = (unit 0..127) x (j-half jh). Each block owns 64 gate columns.
// ---------------------------------------------------------------------------
__global__ __launch_bounds__(256) void prep2(const float* __restrict__ Wgk2,
                                             const float* __restrict__ bgk2,
                                             const u16* __restrict__ Pb,
                                             u16* __restrict__ qtb,
                                             u16* __restrict__ kinvb,
                                             u16* __restrict__ kdecTb,
                                             float* __restrict__ D) {
  __shared__ float gc[64][65];
  __shared__ u16 kbuf[64][65];
  __shared__ float xs[64][17];
  int bx = blockIdx.x;
  int unit = bx >> 1, jh = bx & 1;
  int c = unit & 15, bh = unit >> 4;
  int b = bh >> 2, h = bh & 3;
  int tid = threadIdx.x;
  int brow = b * T_ + c * CHUNK;
  size_t gbase = (size_t)brow * 512 + h * 128 + jh * 64;

#pragma unroll
  for (int e = 0; e < 4; ++e) {
    int idx = e * 256 + tid;
    int i = idx >> 4, r = idx & 15;
    xs[i][r] = bf2f(Pb[(size_t)(brow + i) * PN + 3072 + r]);
  }
  __syncthreads();
  // pass 1: log-sigmoid gates for 64 cols, 4 rows per thread-slot
  {
    int j = tid & 63, i0 = tid >> 6;
    int n = h * 128 + jh * 64 + j;
    float w2[LR_];
#pragma unroll
    for (int r = 0; r < LR_; ++r) w2[r] = Wgk2[r * DK_ + n];
    float bb = bgk2[n];
#pragma unroll 4
    for (int e = 0; e < 16; ++e) {
      int i = e * 4 + i0;
      float sv = bb;
#pragma unroll
      for (int r = 0; r < LR_; ++r) sv = fmaf(xs[i][r], w2[r], sv);
      float ls = fminf(sv, 0.f) - log1pf(__expf(-fabsf(sv)));
      gc[i][j] = ls * (1.0f / 16.0f);
    }
  }
  __syncthreads();
  if (tid < 64) {
    float g = 0.f;
    for (int i = 0; i < 64; ++i) { g += gc[i][tid]; gc[i][tid] = g; }
    D[unit * 128 + jh * 64 + tid] = __expf(g);
  }
  __syncthreads();

  const float scale = 0.08838834764831845f;
  const u16* Pq = Pb + (size_t)brow * PN + h * 128 + jh * 64;
  const u16* Pk = Pq + 512;
#pragma unroll 4
  for (int e = 0; e < 16; ++e) {
    int idx = e * 256 + tid;
    int i = idx >> 6, j = idx & 63;
    float gv = gc[i][j];
    u16 ku = Pk[(size_t)i * PN + j];
    kbuf[i][j] = ku;
    float qv = bf2f(Pq[(size_t)i * PN + j]);
    float kv = bf2f(ku);
    qtb[gbase + (size_t)i * 512 + j]   = f2bf(qv * __expf(gv) * scale);
    kinvb[gbase + (size_t)i * 512 + j] = f2bf(kv * __expf(-gv));
  }
  __syncthreads();
  u16* kd = kdecTb + (size_t)unit * 8192 + (size_t)(jh * 64) * 64;
#pragma unroll 4
  for (int e = 0; e < 16; ++e) {
    int idx = e * 256 + tid;
    int j = idx >> 6, i = idx & 63;
    float kv = bf2f(kbuf[i][j]);
    float gv = gc[i][j];
    float G  = gc[63][j];
    kd[(size_t)j * 64 + i] = f2bf(kv * __expf(G - gv));
  }
}

// ---------------------------------------------------------------------------
// state_combine: per (kh, vs, bh) block, V^T slice resident in LDS; for each
// chunk c: U = KdecT@V (MFMA, KdecT double-buffered), S = D*S + U in regs,
// StT[c+1] written bf16. Slot 0 zeroed. grid (2, 16, 8).
// ---------------------------------------------------------------------------
__global__ __launch_bounds__(256) void state_combine(const u16* __restrict__ Vtb,
                                                     const u16* __restrict__ kdecTb,
                                                     const float* __restrict__ D,
                                                     u16* __restrict__ StT) {
  __shared__ u16 VtS[16384];    // 16 v-rows x 1024 t (chunk-swizzled)
  __shared__ u16 Kdb[2][4096];  // 64 k-rows x 64 t, double-buffered
  int kh = blockIdx.x, vs = blockIdx.y, bh = blockIdx.z;
  int tid = threadIdx.x, w = tid >> 6, l = tid & 63;
  int lrow = l & 15, g4 = l >> 4;
  int unit0 = bh * 16;

  {
    const u16* base = Vtb + (size_t)bh * 262144 + (size_t)(vs * 16) * 1024;
#pragma unroll
    for (int i = 0; i < 8; ++i) {
      int slin = i * 256 + w * 64 + l;
      int row = slin >> 7, chd = slin & 127;
      gll16(base + (size_t)row * 1024 + ((chd ^ (row & 7)) << 3),
            (char*)VtS + i * 4096 + (w << 10));
    }
  }
  int vc = vs * 16 + lrow;
  int kd0 = kh * 64 + w * 16 + (g4 << 2);
  {
    u16x4 z = {0, 0, 0, 0};
    *(u16x4*)&StT[(size_t)bh * 32768 + (size_t)vc * 128 + kd0] = z;
  }
  {
    const u16* kb = kdecTb + (size_t)unit0 * 8192 + (size_t)(kh * 64) * 64;
#pragma unroll
    for (int i = 0; i < 2; ++i) {
      int slin = i * 256 + w * 64 + l;
      int row = slin >> 3, chd = slin & 7;
      gll16(kb + (size_t)row * 64 + ((chd ^ (row & 7)) << 3),
            (char*)Kdb[0] + i * 4096 + (w << 10));
    }
  }
  f32x4 S = {};
  int cur = 0;
  for (int c = 0; c < 15; ++c) {
    __syncthreads();
    if (c < 14) {
      const u16* kb = kdecTb + (size_t)(unit0 + c + 1) * 8192 + (size_t)(kh * 64) * 64;
#pragma unroll
      for (int i = 0; i < 2; ++i) {
        int slin = i * 256 + w * 64 + l;
        int row = slin >> 3, chd = slin & 7;
        gll16(kb + (size_t)row * 64 + ((chd ^ (row & 7)) << 3),
              (char*)Kdb[cur ^ 1] + i * 4096 + (w << 10));
      }
    }
    const u16* Kc = Kdb[cur];
    f32x4 acc = {};
#pragma unroll
    for (int ks = 0; ks < 2; ++ks) {
      int cidx = c * 8 + ks * 4 + g4;
      bf16x8 bv = *(const bf16x8*)(VtS + lrow * 1024 + ((cidx ^ (lrow & 7)) << 3));
      int row = w * 16 + lrow;
      bf16x8 av = *(const bf16x8*)(Kc + row * 64 + ((((ks << 2) + g4) ^ (row & 7)) << 3));
      acc = __builtin_amdgcn_mfma_f32_16x16x32_bf16(av, bv, acc, 0, 0, 0);
    }
    float4 dv = *(const float4*)&D[(size_t)(unit0 + c) * 128 + kd0];
    S[0] = fmaf(dv.x, S[0], acc[0]);
    S[1] = fmaf(dv.y, S[1], acc[1]);
    S[2] = fmaf(dv.z, S[2], acc[2]);
    S[3] = fmaf(dv.w, S[3], acc[3]);
    u16x4 o = {f2bf(S[0]), f2bf(S[1]), f2bf(S[2]), f2bf(S[3])};
    *(u16x4*)&StT[((size_t)(c + 1) * 8 + bh) * 32768 + (size_t)vc * 128 + kd0] = o;
    cur ^= 1;
  }
}

// ---------------------------------------------------------------------------
// Fused per-half-unit: A = mask(Q~ Kinv^T); O = A V + Q~ S; RMSNorm*gw*swish.
// grid 256 = (unit) x (row-half s). 32 rows x 256 v-cols per block.
// ---------------------------------------------------------------------------
__global__ __launch_bounds__(256) void fused_out(const u16* __restrict__ qtb,
                                                 const u16* __restrict__ kinvb,
                                                 const u16* __restrict__ Vtb,
                                                 const u16* __restrict__ StTb,
                                                 const u16* __restrict__ Pb,
                                                 const float* __restrict__ gw,
                                                 u16* __restrict__ onb) {
  __shared__ u16 Qs[4096];
  __shared__ u16 As[2048];
  __shared__ float rsum[32][4];
  int bx = blockIdx.x;
  int unit = bx >> 1, s = bx & 1;
  int c = unit & 15, bh = unit >> 4;
  int b = bh >> 2, h = bh & 3;
  int tid = threadIdx.x, w = tid >> 6, l = tid & 63;
  int lrow = l & 15, g4 = l >> 4, lx = l & 7;
  int crow = b * T_ + c * CHUNK;
  int brow = crow + s * 32;

  {
    int r0 = tid >> 4;
    int csrc = ((tid & 15) ^ (r0 & 7)) << 3;
    const u16* src = qtb + (size_t)(brow + r0) * 512 + h * 128 + csrc;
    gll16(src, (char*)Qs + (w << 10));
    gll16(src + 16 * 512, (char*)Qs + 4096 + (w << 10));
  }
  const u16* Kbase = kinvb + (size_t)crow * 512 + h * 128;
  int wc1 = w & 1, fr = w >> 1;
  bf16x8 bk[2][4];
#pragma unroll
  for (int nj = 0; nj < 2; ++nj)
#pragma unroll
    for (int ks = 0; ks < 4; ++ks)
      bk[nj][ks] = *(const bf16x8*)(Kbase + (size_t)(wc1 * 32 + nj * 16 + lrow) * 512 + ks * 32 + (g4 << 3));
  __syncthreads();

  f32x4 accA[2] = {};
#pragma unroll
  for (int ks = 0; ks < 4; ++ks) {
    int arow = fr * 16 + lrow;
    bf16x8 aq = *(const bf16x8*)(Qs + arow * 128 + ((((ks << 2) + g4) ^ lx) << 3));
#pragma unroll
    for (int nj = 0; nj < 2; ++nj)
      accA[nj] = __builtin_amdgcn_mfma_f32_16x16x32_bf16(aq, bk[nj][ks], accA[nj], 0, 0, 0);
  }
#pragma unroll
  for (int nj = 0; nj < 2; ++nj)
#pragma unroll
    for (int j = 0; j < 4; ++j) {
      int rg = fr * 16 + (g4 << 2) + j;
      int col = wc1 * 32 + nj * 16 + lrow;
      float vv = (col <= s * 32 + rg) ? accA[nj][j] : 0.f;
      int chunk = (col >> 3) ^ (rg & 7);
      As[rg * 64 + (chunk << 3) + (lrow & 7)] = f2bf(vv);
    }
  __syncthreads();

  f32x4 acc[2][4] = {};
  const u16* Vbase = Vtb + (size_t)bh * 262144 + (size_t)(w * 64) * 1024 + c * 64;
  const u16* Sbase = StTb + (((size_t)(c * 8 + bh)) * 256 + w * 64) * 128;
#pragma unroll
  for (int ks2 = 0; ks2 < 2; ++ks2) {
    bf16x8 bv[4];
#pragma unroll
    for (int nj = 0; nj < 4; ++nj)
      bv[nj] = *(const bf16x8*)(Vbase + (size_t)(nj * 16 + lrow) * 1024 + ks2 * 32 + (g4 << 3));
#pragma unroll
    for (int mi = 0; mi < 2; ++mi) {
      int row = mi * 16 + lrow;
      bf16x8 aa = *(const bf16x8*)(As + row * 64 + ((((ks2 << 2) + g4) ^ lx) << 3));
#pragma unroll
      for (int nj = 0; nj < 4; ++nj)
        acc[mi][nj] = __builtin_amdgcn_mfma_f32_16x16x32_bf16(aa, bv[nj], acc[mi][nj], 0, 0, 0);
    }
  }
#pragma unroll
  for (int ks = 0; ks < 4; ++ks) {
    bf16x8 bs[4];
#pragma unroll
    for (int nj = 0; nj < 4; ++nj)
      bs[nj] = *(const bf16x8*)(Sbase + (size_t)(nj * 16 + lrow) * 128 + ks * 32 + (g4 << 3));
#pragma unroll
    for (int mi = 0; mi < 2; ++mi) {
      int row = mi * 16 + lrow;
      bf16x8 aq = *(const bf16x8*)(Qs + row * 128 + ((((ks << 2) + g4) ^ lx) << 3));
#pragma unroll
      for (int nj = 0; nj < 4; ++nj)
        acc[mi][nj] = __builtin_amdgcn_mfma_f32_16x16x32_bf16(aq, bs[nj], acc[mi][nj], 0, 0, 0);
    }
  }

#pragma unroll
  for (int mi = 0; mi < 2; ++mi)
#pragma unroll
    for (int j = 0; j < 4; ++j) {
      float ss = 0.f;
#pragma unroll
      for (int nj = 0; nj < 4; ++nj) { float o = acc[mi][nj][j]; ss = fmaf(o, o, ss); }
      ss += __shfl_xor(ss, 1);
      ss += __shfl_xor(ss, 2);
      ss += __shfl_xor(ss, 4);
      ss += __shfl_xor(ss, 8);
      if (lrow == 0) rsum[mi * 16 + (g4 << 2) + j][w] = ss;
    }
  __syncthreads();
  const u16* Gbase = Pb + (size_t)brow * PN + 2048 + h * 256;
#pragma unroll
  for (int mi = 0; mi < 2; ++mi)
#pragma unroll
    for (int j = 0; j < 4; ++j) {
      int row = mi * 16 + (g4 << 2) + j;
      float4 rs = *(float4*)&rsum[row][0];
      float rn = rsqrtf((rs.x + rs.y + rs.z + rs.w) * (1.f / 256.f) + 1e-5f);
#pragma unroll
      for (int nj = 0; nj < 4; ++nj) {
        int vc = w * 64 + nj * 16 + lrow;
        float o = acc[mi][nj][j] * rn * gw[vc];
        float gval = bf2f(Gbase[(size_t)row * PN + vc]);
        float sw = gval / (1.f + __expf(-gval));
        onb[(size_t)(brow + row) * 1024 + h * 256 + vc] = f2bf(o * sw);
      }
    }
}

// ---------------------------------------------------------------------------
extern "C" void kernel_launch(void* const* d_in, const int* in_sizes, int n_in,
                              void* d_out, int out_size, void* d_ws, size_t ws_size,
                              hipStream_t stream) {
  const float* x    = (const float*)d_in[0];
  const float* Wq   = (const float*)d_in[1];
  const float* Wk   = (const float*)d_in[2];
  const float* Wv   = (const float*)d_in[3];
  const float* Wgk1 = (const float*)d_in[4];
  const float* Wgk2 = (const float*)d_in[5];
  const float* bgk2 = (const float*)d_in[6];
  const float* Wg   = (const float*)d_in[7];
  const float* Wo   = (const float*)d_in[8];
  const float* gw   = (const float*)d_in[9];
  float* out = (float*)d_out;

  float* F = (float*)d_ws;
  u16*   Pb     = (u16*)F;                       // [2048][3200] bf16
  u16*   WallTb = (u16*)(F + 3276800);           // [3200][1024] bf16 -> kdecT+onb
  u16*   Wotb   = (u16*)(F + 4915200);           // [1024][1024] bf16
  u16*   xbb    = (u16*)(F + 5439488);           // x bf16 -> qtb+kinvb
  u16*   Vtb    = (u16*)(F + 6488064);           // [8][256][1024] bf16
  float* D      = F + 7536640;                   // [128][128] f32
  u16*   StT    = (u16*)(F + 7553024);           // [16][8][32768] bf16

  u16* qtb    = xbb;                             // aliases (xbb dead after proj)
  u16* kinvb  = xbb + 1048576;
  u16* kdecTb = WallTb;                          // WallTb dead after proj
  u16* onb    = WallTb + 1048576;

  dim3 blk(256);
  prep_misc<<<dim3(32, 32, 7), blk, 0, stream>>>(x, Wq, Wk, Wv, Wg, Wo, Wgk1,
                                                 xbb, WallTb, Wotb);
  gemm128<true, true><<<dim3(25, 16), blk, 0, stream>>>(xbb, WallTb, Pb, Vtb, 2048, PN, H_);
  prep2<<<256, blk, 0, stream>>>(Wgk2, bgk2, Pb, qtb, kinvb, kdecTb, D);
  state_combine<<<dim3(2, 16, 8), blk, 0, stream>>>(Vtb, kdecTb, D, StT);
  fused_out<<<256, blk, 0, stream>>>(qtb, kinvb, Vtb, StT, Pb, gw, onb);
  gemmWo<<<dim3(16, 16), blk, 0, stream>>>(onb, Wotb, out, 2048, H_, DV_);
}

// Round 8
// 93.192 us; speedup vs baseline: 10.8880x; 1.0265x over previous
//
#include <hip/hip_runtime.h>
#include <math.h>

#define T_  1024
#define H_  1024
#define DK_ 512
#define DV_ 1024
#define LR_ 16
#define CHUNK 64
#define PN  3200   // fused projection width: q(512)|k(512)|v(1024)|g(1024)|xg1pad(128)

using f32x4  = __attribute__((ext_vector_type(4))) float;
using f32x16 = __attribute__((ext_vector_type(16))) float;
using bf16x8 = __attribute__((ext_vector_type(8))) short;
using u16x4  = __attribute__((ext_vector_type(4))) unsigned short;
typedef unsigned short u16;

__device__ __forceinline__ u16 f2bf(float f) {
  union { float f; unsigned int u; } v; v.f = f;
  unsigned int r = v.u + 0x7FFF + ((v.u >> 16) & 1);
  return (u16)(r >> 16);
}
__device__ __forceinline__ float bf2f(u16 u) {
  union { unsigned int i; float f; } v; v.i = ((unsigned int)u) << 16;
  return v.f;
}
__device__ __forceinline__ void gll16(const void* g, void* l) {
  __builtin_amdgcn_global_load_lds((const __attribute__((address_space(1))) void*)g,
                                   (__attribute__((address_space(3))) void*)l, 16, 0, 0);
}

// ---------------------------------------------------------------------------
// 128x128-tile bf16 GEMM via mfma_f32_32x32x16, 2-phase double-buffered LDS.
// C[M,N] = A[M,K] @ Bt[N,K]. BK=64, 4 waves, wave = 2x2 of 32x32 frags.
// VT: blocks in the V column range also emit the transposed tile to Vtb.
// ---------------------------------------------------------------------------
template <bool OBF, bool VT>
__global__ __launch_bounds__(256) void gemm128(const u16* __restrict__ A,
                                               const u16* __restrict__ Bt,
                                               void* __restrict__ Cv,
                                               u16* __restrict__ Vtb,
                                               int M, int N, int K) {
  __shared__ u16 Asm[2][8192];   // 2 x (128 x 64)
  __shared__ u16 Bsm[2][8192];
  int tid = threadIdx.x, w = tid >> 6, l = tid & 63;
  int bm = blockIdx.y << 7, bn = blockIdx.x << 7;

  int srow = (w << 3) + (l >> 3);
  int schunk = ((l & 7) ^ (l >> 3)) << 3;
  const u16* pA = A  + (size_t)(bm + srow) * K + schunk;
  const u16* pB = Bt + (size_t)(bn + srow) * K + schunk;
  char* AsmB = (char*)Asm;
  char* BsmB = (char*)Bsm;
  int ldsw = w << 10;

  int wr = w >> 1, wc = w & 1;
  int l31 = l & 31, hi = l >> 5;

  int nt = K >> 6;
  // prologue: stage tile 0 into buffer 0
#pragma unroll
  for (int i = 0; i < 4; ++i) {
    gll16(pA + (size_t)(i * 32) * K, AsmB + i * 4096 + ldsw);
    gll16(pB + (size_t)(i * 32) * K, BsmB + i * 4096 + ldsw);
  }
  __syncthreads();

  f32x16 acc[2][2] = {};
  int cur = 0;
  for (int t = 0; t < nt; ++t) {
    if (t + 1 < nt) {             // issue next-tile loads into the other buffer
      int k0 = (t + 1) << 6;
      int off = (cur ^ 1) << 14;  // 16384 B per buffer
#pragma unroll
      for (int i = 0; i < 4; ++i) {
        gll16(pA + (size_t)(i * 32) * K + k0, AsmB + off + i * 4096 + ldsw);
        gll16(pB + (size_t)(i * 32) * K + k0, BsmB + off + i * 4096 + ldsw);
      }
    }
    const u16* Ac = Asm[cur];
    const u16* Bc = Bsm[cur];
    bf16x8 a[2][4], b[2][4];
#pragma unroll
    for (int mi = 0; mi < 2; ++mi)
#pragma unroll
      for (int ks = 0; ks < 4; ++ks) {
        int ar = wr * 64 + mi * 32 + l31;
        int br = wc * 64 + mi * 32 + l31;
        a[mi][ks] = *(const bf16x8*)(Ac + ar * 64 + ((((ks << 1) + hi) ^ (ar & 7)) << 3));
        b[mi][ks] = *(const bf16x8*)(Bc + br * 64 + ((((ks << 1) + hi) ^ (br & 7)) << 3));
      }
#pragma unroll
    for (int ks = 0; ks < 4; ++ks)
#pragma unroll
      for (int mi = 0; mi < 2; ++mi)
#pragma unroll
        for (int ni = 0; ni < 2; ++ni)
          acc[mi][ni] = __builtin_amdgcn_mfma_f32_32x32x16_bf16(
              a[mi][ks], b[ni][ks], acc[mi][ni], 0, 0, 0);
    __syncthreads();              // drains prefetch (vmcnt 0) + read-completion
    cur ^= 1;
  }
  // C/D: col = l&31, row = (reg&3) + 8*(reg>>2) + 4*(l>>5)
#pragma unroll
  for (int mi = 0; mi < 2; ++mi)
#pragma unroll
    for (int ni = 0; ni < 2; ++ni) {
      int colg = bn + wc * 64 + ni * 32 + l31;
#pragma unroll
      for (int q = 0; q < 4; ++q) {
        int row0 = bm + wr * 64 + mi * 32 + q * 8 + hi * 4;
#pragma unroll
        for (int j = 0; j < 4; ++j) {
          float vv = acc[mi][ni][q * 4 + j];
          if (OBF) ((u16*)Cv)[(size_t)(row0 + j) * N + colg] = f2bf(vv);
          else     ((float*)Cv)[(size_t)(row0 + j) * N + colg] = vv;
        }
      }
    }
  if (VT && bn >= 1024 && bn < 2048) {   // also emit V^T for this tile
    int h = (bn - 1024) >> 8;
    int bb_ = bm >> 10;
    u16* vt = Vtb + (size_t)(bb_ * 4 + h) * 262144;
    int tbase = bm & 1023;
#pragma unroll
    for (int mi = 0; mi < 2; ++mi)
#pragma unroll
      for (int ni = 0; ni < 2; ++ni) {
        int vcl = ((bn - 1024) & 255) + wc * 64 + ni * 32 + l31;
#pragma unroll
        for (int q = 0; q < 4; ++q) {
          int t0 = tbase + wr * 64 + mi * 32 + q * 8 + hi * 4;
          u16x4 o = {f2bf(acc[mi][ni][q * 4 + 0]), f2bf(acc[mi][ni][q * 4 + 1]),
                     f2bf(acc[mi][ni][q * 4 + 2]), f2bf(acc[mi][ni][q * 4 + 3])};
          *(u16x4*)&vt[(size_t)vcl * 1024 + t0] = o;
        }
      }
  }
}

// ---------------------------------------------------------------------------
// 128x64-tile bf16 GEMM (final Wo), 2-phase double-buffered. grid (16,16).
// 4 waves, wave w owns rows [w*32,+32) x all 64 cols = 1x2 of 32x32 frags.
// ---------------------------------------------------------------------------
__global__ __launch_bounds__(256) void gemmWo(const u16* __restrict__ A,
                                              const u16* __restrict__ Bt,
                                              float* __restrict__ C,
                                              int M, int N, int K) {
  __shared__ u16 Asm[2][8192];   // 2 x (128 x 64)
  __shared__ u16 Bsm[2][4096];   // 2 x (64 x 64)
  int tid = threadIdx.x, w = tid >> 6, l = tid & 63;
  int bm = blockIdx.y << 7, bn = blockIdx.x << 6;

  int srow = (w << 3) + (l >> 3);
  int schunk = ((l & 7) ^ (l >> 3)) << 3;
  const u16* pA = A  + (size_t)(bm + srow) * K + schunk;
  const u16* pB = Bt + (size_t)(bn + srow) * K + schunk;
  char* AsmB = (char*)Asm;
  char* BsmB = (char*)Bsm;
  int ldsw = w << 10;
  int l31 = l & 31, hi = l >> 5;

  int nt = K >> 6;
#pragma unroll
  for (int i = 0; i < 4; ++i)
    gll16(pA + (size_t)(i * 32) * K, AsmB + i * 4096 + ldsw);
#pragma unroll
  for (int i = 0; i < 2; ++i)
    gll16(pB + (size_t)(i * 32) * K, BsmB + i * 4096 + ldsw);
  __syncthreads();

  f32x16 acc[2] = {};
  int cur = 0;
  for (int t = 0; t < nt; ++t) {
    if (t + 1 < nt) {
      int k0 = (t + 1) << 6;
#pragma unroll
      for (int i = 0; i < 4; ++i)
        gll16(pA + (size_t)(i * 32) * K + k0, AsmB + ((cur ^ 1) << 14) + i * 4096 + ldsw);
#pragma unroll
      for (int i = 0; i < 2; ++i)
        gll16(pB + (size_t)(i * 32) * K + k0, BsmB + ((cur ^ 1) << 13) + i * 4096 + ldsw);
    }
    const u16* Ac = Asm[cur];
    const u16* Bc = Bsm[cur];
    bf16x8 a[4], b[2][4];
#pragma unroll
    for (int ks = 0; ks < 4; ++ks) {
      int ar = w * 32 + l31;
      a[ks] = *(const bf16x8*)(Ac + ar * 64 + ((((ks << 1) + hi) ^ (ar & 7)) << 3));
#pragma unroll
      for (int ni = 0; ni < 2; ++ni) {
        int br = ni * 32 + l31;
        b[ni][ks] = *(const bf16x8*)(Bc + br * 64 + ((((ks << 1) + hi) ^ (br & 7)) << 3));
      }
    }
#pragma unroll
    for (int ks = 0; ks < 4; ++ks)
#pragma unroll
      for (int ni = 0; ni < 2; ++ni)
        acc[ni] = __builtin_amdgcn_mfma_f32_32x32x16_bf16(a[ks], b[ni][ks], acc[ni], 0, 0, 0);
    __syncthreads();
    cur ^= 1;
  }
#pragma unroll
  for (int ni = 0; ni < 2; ++ni) {
    int colg = bn + ni * 32 + l31;
#pragma unroll
    for (int q = 0; q < 4; ++q) {
      int row0 = bm + w * 32 + q * 8 + hi * 4;
#pragma unroll
      for (int j = 0; j < 4; ++j)
        C[(size_t)(row0 + j) * N + colg] = acc[ni][q * 4 + j];
    }
  }
}

// ---------------------------------------------------------------------------
// Fused misc prep: z=0..3 weight transposes into fused WallTb, z=4 Wo->Wotb,
// z=5 x->bf16, z=6 Wgk1^T zero-padded into WallTb rows 3072..3199.
// ---------------------------------------------------------------------------
__global__ __launch_bounds__(256) void prep_misc(const float* __restrict__ x,
                                                 const float* __restrict__ Wq,
                                                 const float* __restrict__ Wk,
                                                 const float* __restrict__ Wv,
                                                 const float* __restrict__ Wg,
                                                 const float* __restrict__ Wo,
                                                 const float* __restrict__ Wgk1,
                                                 u16* __restrict__ xbb,
                                                 u16* __restrict__ WallTb,
                                                 u16* __restrict__ Wotb) {
  int z = blockIdx.z;
  int tid = threadIdx.x;
  if (z == 5) {
    size_t i0 = ((size_t)(blockIdx.y * 32 + blockIdx.x)) * 2048 + tid * 4;
    float4 v0 = *(const float4*)&x[i0];
    float4 v1 = *(const float4*)&x[i0 + 1024];
    u16x4 o0 = {f2bf(v0.x), f2bf(v0.y), f2bf(v0.z), f2bf(v0.w)};
    u16x4 o1 = {f2bf(v1.x), f2bf(v1.y), f2bf(v1.z), f2bf(v1.w)};
    *(u16x4*)&xbb[i0] = o0;
    *(u16x4*)&xbb[i0 + 1024] = o1;
    return;
  }
  if (z == 6) {
    if (blockIdx.x != 0) return;
    int col = blockIdx.y * 32 + (tid & 31);
#pragma unroll
    for (int i = 0; i < 16; ++i) {
      int rr = (tid >> 5) + i * 8;   // 0..127
      float v = (rr < LR_) ? Wgk1[(size_t)col * LR_ + rr] : 0.f;
      WallTb[(size_t)(3072 + rr) * 1024 + col] = f2bf(v);
    }
    return;
  }
  const float* in; u16* outp; int C;
  if (z == 0)      { in = Wq; outp = WallTb;               C = 512; }
  else if (z == 1) { in = Wk; outp = WallTb + 512 * 1024;  C = 512; }
  else if (z == 2) { in = Wv; outp = WallTb + 1024 * 1024; C = 1024; }
  else if (z == 3) { in = Wg; outp = WallTb + 2048 * 1024; C = 1024; }
  else             { in = Wo; outp = Wotb;                 C = 1024; }
  int bx = blockIdx.x << 5, by = blockIdx.y << 5;
  if (bx >= C) return;
  __shared__ float tile[32][33];
  int tx = tid & 31, ty = tid >> 5;
#pragma unroll
  for (int i = 0; i < 32; i += 8)
    tile[ty + i][tx] = in[(size_t)(by + ty + i) * C + bx + tx];
  __syncthreads();
#pragma unroll
  for (int i = 0; i < 32; i += 8)
    outp[(size_t)(bx + ty + i) * 1024 + by + tx] = f2bf(tile[tx][ty + i]);
}

// ---------------------------------------------------------------------------
// prep2: gate (xg1@Wgk2+b -> logsigmoid/16 -> prefix), bf16 Q~/Kinv/KdecT, D.
// grid 256 = (unit 0..127) x (j-half jh). Each block owns 64 gate columns.
// ---------------------------------------------------------------------------
__global__ __launch_bounds__(256) void prep2(const float* __restrict__ Wgk2,
                                             const float* __restrict__ bgk2,
                                             const u16* __restrict__ Pb,
                                             u16* __restrict__ qtb,
                                             u16* __restrict__ kinvb,
                                             u16* __restrict__ kdecTb,
                                             float* __restrict__ D) {
  __shared__ float gc[64][65];
  __shared__ u16 kbuf[64][65];
  __shared__ float xs[64][17];
  int bx = blockIdx.x;
  int unit = bx >> 1, jh = bx & 1;
  int c = unit & 15, bh = unit >> 4;
  int b = bh >> 2, h = bh & 3;
  int tid = threadIdx.x;
  int brow = b * T_ + c * CHUNK;
  size_t gbase = (size_t)brow * 512 + h * 128 + jh * 64;

#pragma unroll
  for (int e = 0; e < 4; ++e) {
    int idx = e * 256 + tid;
    int i = idx >> 4, r = idx & 15;
    xs[i][r] = bf2f(Pb[(size_t)(brow + i) * PN + 3072 + r]);
  }
  __syncthreads();
  {
    int j = tid & 63, i0 = tid >> 6;
    int n = h * 128 + jh * 64 + j;
    float w2[LR_];
#pragma unroll
    for (int r = 0; r < LR_; ++r) w2[r] = Wgk2[r * DK_ + n];
    float bb = bgk2[n];
#pragma unroll 4
    for (int e = 0; e < 16; ++e) {
      int i = e * 4 + i0;
      float sv = bb;
#pragma unroll
      for (int r = 0; r < LR_; ++r) sv = fmaf(xs[i][r], w2[r], sv);
      float ls = fminf(sv, 0.f) - log1pf(__expf(-fabsf(sv)));
      gc[i][j] = ls * (1.0f / 16.0f);
    }
  }
  __syncthreads();
  if (tid < 64) {
    float g = 0.f;
    for (int i = 0; i < 64; ++i) { g += gc[i][tid]; gc[i][tid] = g; }
    D[unit * 128 + jh * 64 + tid] = __expf(g);
  }
  __syncthreads();

  const float scale = 0.08838834764831845f;
  const u16* Pq = Pb + (size_t)brow * PN + h * 128 + jh * 64;
  const u16* Pk = Pq + 512;
#pragma unroll 4
  for (int e = 0; e < 16; ++e) {
    int idx = e * 256 + tid;
    int i = idx >> 6, j = idx & 63;
    float gv = gc[i][j];
    u16 ku = Pk[(size_t)i * PN + j];
    kbuf[i][j] = ku;
    float qv = bf2f(Pq[(size_t)i * PN + j]);
    float kv = bf2f(ku);
    qtb[gbase + (size_t)i * 512 + j]   = f2bf(qv * __expf(gv) * scale);
    kinvb[gbase + (size_t)i * 512 + j] = f2bf(kv * __expf(-gv));
  }
  __syncthreads();
  u16* kd = kdecTb + (size_t)unit * 8192 + (size_t)(jh * 64) * 64;
#pragma unroll 4
  for (int e = 0; e < 16; ++e) {
    int idx = e * 256 + tid;
    int j = idx >> 6, i = idx & 63;
    float kv = bf2f(kbuf[i][j]);
    float gv = gc[i][j];
    float G  = gc[63][j];
    kd[(size_t)j * 64 + i] = f2bf(kv * __expf(G - gv));
  }
}

// ---------------------------------------------------------------------------
// state_combine: per (kh, vs, bh) block, V^T slice resident in LDS; for each
// chunk c: U = KdecT@V (MFMA, KdecT double-buffered), S = D*S + U in regs,
// StT[c+1] written bf16. Slot 0 zeroed. grid (2, 16, 8).
// ---------------------------------------------------------------------------
__global__ __launch_bounds__(256) void state_combine(const u16* __restrict__ Vtb,
                                                     const u16* __restrict__ kdecTb,
                                                     const float* __restrict__ D,
                                                     u16* __restrict__ StT) {
  __shared__ u16 VtS[16384];    // 16 v-rows x 1024 t (chunk-swizzled)
  __shared__ u16 Kdb[2][4096];  // 64 k-rows x 64 t, double-buffered
  int kh = blockIdx.x, vs = blockIdx.y, bh = blockIdx.z;
  int tid = threadIdx.x, w = tid >> 6, l = tid & 63;
  int lrow = l & 15, g4 = l >> 4;
  int unit0 = bh * 16;

  {
    const u16* base = Vtb + (size_t)bh * 262144 + (size_t)(vs * 16) * 1024;
#pragma unroll
    for (int i = 0; i < 8; ++i) {
      int slin = i * 256 + w * 64 + l;
      int row = slin >> 7, chd = slin & 127;
      gll16(base + (size_t)row * 1024 + ((chd ^ (row & 7)) << 3),
            (char*)VtS + i * 4096 + (w << 10));
    }
  }
  int vc = vs * 16 + lrow;
  int kd0 = kh * 64 + w * 16 + (g4 << 2);
  {
    u16x4 z = {0, 0, 0, 0};
    *(u16x4*)&StT[(size_t)bh * 32768 + (size_t)vc * 128 + kd0] = z;
  }
  {
    const u16* kb = kdecTb + (size_t)unit0 * 8192 + (size_t)(kh * 64) * 64;
#pragma unroll
    for (int i = 0; i < 2; ++i) {
      int slin = i * 256 + w * 64 + l;
      int row = slin >> 3, chd = slin & 7;
      gll16(kb + (size_t)row * 64 + ((chd ^ (row & 7)) << 3),
            (char*)Kdb[0] + i * 4096 + (w << 10));
    }
  }
  f32x4 S = {};
  int cur = 0;
  for (int c = 0; c < 15; ++c) {
    __syncthreads();
    if (c < 14) {
      const u16* kb = kdecTb + (size_t)(unit0 + c + 1) * 8192 + (size_t)(kh * 64) * 64;
#pragma unroll
      for (int i = 0; i < 2; ++i) {
        int slin = i * 256 + w * 64 + l;
        int row = slin >> 3, chd = slin & 7;
        gll16(kb + (size_t)row * 64 + ((chd ^ (row & 7)) << 3),
              (char*)Kdb[cur ^ 1] + i * 4096 + (w << 10));
      }
    }
    const u16* Kc = Kdb[cur];
    f32x4 acc = {};
#pragma unroll
    for (int ks = 0; ks < 2; ++ks) {
      int cidx = c * 8 + ks * 4 + g4;
      bf16x8 bv = *(const bf16x8*)(VtS + lrow * 1024 + ((cidx ^ (lrow & 7)) << 3));
      int row = w * 16 + lrow;
      bf16x8 av = *(const bf16x8*)(Kc + row * 64 + ((((ks << 2) + g4) ^ (row & 7)) << 3));
      acc = __builtin_amdgcn_mfma_f32_16x16x32_bf16(av, bv, acc, 0, 0, 0);
    }
    float4 dv = *(const float4*)&D[(size_t)(unit0 + c) * 128 + kd0];
    S[0] = fmaf(dv.x, S[0], acc[0]);
    S[1] = fmaf(dv.y, S[1], acc[1]);
    S[2] = fmaf(dv.z, S[2], acc[2]);
    S[3] = fmaf(dv.w, S[3], acc[3]);
    u16x4 o = {f2bf(S[0]), f2bf(S[1]), f2bf(S[2]), f2bf(S[3])};
    *(u16x4*)&StT[((size_t)(c + 1) * 8 + bh) * 32768 + (size_t)vc * 128 + kd0] = o;
    cur ^= 1;
  }
}

// ---------------------------------------------------------------------------
// Fused per-half-unit: A = mask(Q~ Kinv^T); O = A V + Q~ S; RMSNorm*gw*swish.
// grid 256 = (unit) x (row-half s). 32 rows x 256 v-cols per block.
// ---------------------------------------------------------------------------
__global__ __launch_bounds__(256) void fused_out(const u16* __restrict__ qtb,
                                                 const u16* __restrict__ kinvb,
                                                 const u16* __restrict__ Vtb,
                                                 const u16* __restrict__ StTb,
                                                 const u16* __restrict__ Pb,
                                                 const float* __restrict__ gw,
                                                 u16* __restrict__ onb) {
  __shared__ u16 Qs[4096];
  __shared__ u16 As[2048];
  __shared__ float rsum[32][4];
  int bx = blockIdx.x;
  int unit = bx >> 1, s = bx & 1;
  int c = unit & 15, bh = unit >> 4;
  int b = bh >> 2, h = bh & 3;
  int tid = threadIdx.x, w = tid >> 6, l = tid & 63;
  int lrow = l & 15, g4 = l >> 4, lx = l & 7;
  int crow = b * T_ + c * CHUNK;
  int brow = crow + s * 32;

  {
    int r0 = tid >> 4;
    int csrc = ((tid & 15) ^ (r0 & 7)) << 3;
    const u16* src = qtb + (size_t)(brow + r0) * 512 + h * 128 + csrc;
    gll16(src, (char*)Qs + (w << 10));
    gll16(src + 16 * 512, (char*)Qs + 4096 + (w << 10));
  }
  const u16* Kbase = kinvb + (size_t)crow * 512 + h * 128;
  int wc1 = w & 1, fr = w >> 1;
  bf16x8 bk[2][4];
#pragma unroll
  for (int nj = 0; nj < 2; ++nj)
#pragma unroll
    for (int ks = 0; ks < 4; ++ks)
      bk[nj][ks] = *(const bf16x8*)(Kbase + (size_t)(wc1 * 32 + nj * 16 + lrow) * 512 + ks * 32 + (g4 << 3));
  __syncthreads();

  f32x4 accA[2] = {};
#pragma unroll
  for (int ks = 0; ks < 4; ++ks) {
    int arow = fr * 16 + lrow;
    bf16x8 aq = *(const bf16x8*)(Qs + arow * 128 + ((((ks << 2) + g4) ^ lx) << 3));
#pragma unroll
    for (int nj = 0; nj < 2; ++nj)
      accA[nj] = __builtin_amdgcn_mfma_f32_16x16x32_bf16(aq, bk[nj][ks], accA[nj], 0, 0, 0);
  }
#pragma unroll
  for (int nj = 0; nj < 2; ++nj)
#pragma unroll
    for (int j = 0; j < 4; ++j) {
      int rg = fr * 16 + (g4 << 2) + j;
      int col = wc1 * 32 + nj * 16 + lrow;
      float vv = (col <= s * 32 + rg) ? accA[nj][j] : 0.f;
      int chunk = (col >> 3) ^ (rg & 7);
      As[rg * 64 + (chunk << 3) + (lrow & 7)] = f2bf(vv);
    }
  __syncthreads();

  f32x4 acc[2][4] = {};
  const u16* Vbase = Vtb + (size_t)bh * 262144 + (size_t)(w * 64) * 1024 + c * 64;
  const u16* Sbase = StTb + (((size_t)(c * 8 + bh)) * 256 + w * 64) * 128;
#pragma unroll
  for (int ks2 = 0; ks2 < 2; ++ks2) {
    bf16x8 bv[4];
#pragma unroll
    for (int nj = 0; nj < 4; ++nj)
      bv[nj] = *(const bf16x8*)(Vbase + (size_t)(nj * 16 + lrow) * 1024 + ks2 * 32 + (g4 << 3));
#pragma unroll
    for (int mi = 0; mi < 2; ++mi) {
      int row = mi * 16 + lrow;
      bf16x8 aa = *(const bf16x8*)(As + row * 64 + ((((ks2 << 2) + g4) ^ lx) << 3));
#pragma unroll
      for (int nj = 0; nj < 4; ++nj)
        acc[mi][nj] = __builtin_amdgcn_mfma_f32_16x16x32_bf16(aa, bv[nj], acc[mi][nj], 0, 0, 0);
    }
  }
#pragma unroll
  for (int ks = 0; ks < 4; ++ks) {
    bf16x8 bs[4];
#pragma unroll
    for (int nj = 0; nj < 4; ++nj)
      bs[nj] = *(const bf16x8*)(Sbase + (size_t)(nj * 16 + lrow) * 128 + ks * 32 + (g4 << 3));
#pragma unroll
    for (int mi = 0; mi < 2; ++mi) {
      int row = mi * 16 + lrow;
      bf16x8 aq = *(const bf16x8*)(Qs + row * 128 + ((((ks << 2) + g4) ^ lx) << 3));
#pragma unroll
      for (int nj = 0; nj < 4; ++nj)
        acc[mi][nj] = __builtin_amdgcn_mfma_f32_16x16x32_bf16(aq, bs[nj], acc[mi][nj], 0, 0, 0);
    }
  }

#pragma unroll
  for (int mi = 0; mi < 2; ++mi)
#pragma unroll
    for (int j = 0; j < 4; ++j) {
      float ss = 0.f;
#pragma unroll
      for (int nj = 0; nj < 4; ++nj) { float o = acc[mi][nj][j]; ss = fmaf(o, o, ss); }
      ss += __shfl_xor(ss, 1);
      ss += __shfl_xor(ss, 2);
      ss += __shfl_xor(ss, 4);
      ss += __shfl_xor(ss, 8);
      if (lrow == 0) rsum[mi * 16 + (g4 << 2) + j][w] = ss;
    }
  __syncthreads();
  const u16* Gbase = Pb + (size_t)brow * PN + 2048 + h * 256;
#pragma unroll
  for (int mi = 0; mi < 2; ++mi)
#pragma unroll
    for (int j = 0; j < 4; ++j) {
      int row = mi * 16 + (g4 << 2) + j;
      float4 rs = *(float4*)&rsum[row][0];
      float rn = rsqrtf((rs.x + rs.y + rs.z + rs.w) * (1.f / 256.f) + 1e-5f);
#pragma unroll
      for (int nj = 0; nj < 4; ++nj) {
        int vc = w * 64 + nj * 16 + lrow;
        float o = acc[mi][nj][j] * rn * gw[vc];
        float gval = bf2f(Gbase[(size_t)row * PN + vc]);
        float sw = gval / (1.f + __expf(-gval));
        onb[(size_t)(brow + row) * 1024 + h * 256 + vc] = f2bf(o * sw);
      }
    }
}

// ---------------------------------------------------------------------------
extern "C" void kernel_launch(void* const* d_in, const int* in_sizes, int n_in,
                              void* d_out, int out_size, void* d_ws, size_t ws_size,
                              hipStream_t stream) {
  const float* x    = (const float*)d_in[0];
  const float* Wq   = (const float*)d_in[1];
  const float* Wk   = (const float*)d_in[2];
  const float* Wv   = (const float*)d_in[3];
  const float* Wgk1 = (const float*)d_in[4];
  const float* Wgk2 = (const float*)d_in[5];
  const float* bgk2 = (const float*)d_in[6];
  const float* Wg   = (const float*)d_in[7];
  const float* Wo   = (const float*)d_in[8];
  const float* gw   = (const float*)d_in[9];
  float* out = (float*)d_out;

  float* F = (float*)d_ws;
  u16*   Pb     = (u16*)F;                       // [2048][3200] bf16
  u16*   WallTb = (u16*)(F + 3276800);           // [3200][1024] bf16 -> kdecT+onb
  u16*   Wotb   = (u16*)(F + 4915200);           // [1024][1024] bf16
  u16*   xbb    = (u16*)(F + 5439488);           // x bf16 -> qtb+kinvb
  u16*   Vtb    = (u16*)(F + 6488064);           // [8][256][1024] bf16
  float* D      = F + 7536640;                   // [128][128] f32
  u16*   StT    = (u16*)(F + 7553024);           // [16][8][32768] bf16

  u16* qtb    = xbb;                             // aliases (xbb dead after proj)
  u16* kinvb  = xbb + 1048576;
  u16* kdecTb = WallTb;                          // WallTb dead after proj
  u16* onb    = WallTb + 1048576;

  dim3 blk(256);
  prep_misc<<<dim3(32, 32, 7), blk, 0, stream>>>(x, Wq, Wk, Wv, Wg, Wo, Wgk1,
                                                 xbb, WallTb, Wotb);
  gemm128<true, true><<<dim3(25, 16), blk, 0, stream>>>(xbb, WallTb, Pb, Vtb, 2048, PN, H_);
  prep2<<<256, blk, 0, stream>>>(Wgk2, bgk2, Pb, qtb, kinvb, kdecTb, D);
  state_combine<<<dim3(2, 16, 8), blk, 0, stream>>>(Vtb, kdecTb, D, StT);
  fused_out<<<256, blk, 0, stream>>>(qtb, kinvb, Vtb, StT, Pb, gw, onb);
  gemmWo<<<dim3(16, 16), blk, 0, stream>>>(onb, Wotb, out, 2048, H_, DV_);
}